// Round 15
// baseline (250.552 us; speedup 1.0000x reference)
//
#include <hip/hip_runtime.h>
#include <math.h>

typedef _Float16 f16;
typedef _Float16 f16x2 __attribute__((ext_vector_type(2)));
typedef _Float16 f16x4 __attribute__((ext_vector_type(4)));
typedef _Float16 f16x8 __attribute__((ext_vector_type(8)));
typedef float f32x2 __attribute__((ext_vector_type(2)));
typedef float f32x4 __attribute__((ext_vector_type(4)));

#define NB   2
#define NS   2048
#define ND   1024
#define NH   16
#define NHD  64
#define EPSF 1e-6f
#define SCL  0.18033688011110793f   // 0.125 * log2(e)
#define EXP2F(x) __builtin_exp2f(x) // lowers to v_exp_f32 (HW is 2^x)

__device__ __forceinline__ void gll16(const void* g, void* l) {
  __builtin_amdgcn_global_load_lds(
      (const __attribute__((address_space(1))) void*)g,
      (__attribute__((address_space(3))) void*)l, 16, 0, 0);
}

// ---------------- fused fp32 -> fp16 convert: 7 tensors, one launch ----------------
struct CvtArgs { const float* src[7]; f16* dst[7]; int n8[7]; };

__global__ void cvt_multi(CvtArgs a) {
  const int ti = blockIdx.y;
  const int i = blockIdx.x * blockDim.x + threadIdx.x;
  if (i >= a.n8[ti]) return;
  const float4* s4 = (const float4*)a.src[ti] + (size_t)i * 2;
  float4 x = s4[0], y = s4[1];
  f16x8 o;
  o[0]=(f16)x.x; o[1]=(f16)x.y; o[2]=(f16)x.z; o[3]=(f16)x.w;
  o[4]=(f16)y.x; o[5]=(f16)y.y; o[6]=(f16)y.z; o[7]=(f16)y.w;
  ((f16x8*)a.dst[ti])[i] = o;
}

// ---------------- GEMM: C[M][N] = A[M][K] * B[N][K]^T + bias ----------------
// 128x128 tile, BK=64, 4 waves, top-sync dbuf + bijective XCD swizzle (T1):
// each XCD gets a contiguous chunk of (x,y,z) blocks -> shared A/B panels stay
// in its private L2 instead of being re-fetched by all 8 XCDs.
struct GemmOps { const f16* A; const f16* Bw; const float* bias; f16* oh; float* of; };
struct GemmBatch { GemmOps op[3]; };

__launch_bounds__(256, 2)
__global__ void gemm_nt_f16(GemmBatch gb, int M, int N, int K) {
  __shared__ f16 As[2][128 * 64];
  __shared__ f16 Bs[2][128 * 64];
  const int t = threadIdx.x;
  const int w = t >> 6, l = t & 63, l15 = l & 15, lg = l >> 4;
  const int wr = w >> 1, wc = w & 1;
  // bijective XCD swizzle over the linearized grid (total % 8 == 0 for all uses)
  const int gxy = gridDim.x * gridDim.y;
  const int total = gxy * gridDim.z;
  const int lid = blockIdx.x + gridDim.x * (blockIdx.y + gridDim.y * blockIdx.z);
  const int swz = (lid & 7) * (total >> 3) + (lid >> 3);
  const int zi = swz / gxy, rem = swz % gxy;
  const int yi = rem / gridDim.x, xi = rem % gridDim.x;
  const GemmOps g = gb.op[zi];
  const int m0 = xi * 128, n0 = yi * 128;
  const f16* A = g.A;
  const f16* Bm = g.Bw;

  auto stage = [&](int k0, int b) {
    for (int i = 0; i < 4; ++i) {
      int idx = i * 256 + t;
      int row = idx >> 3, seg = idx & 7;
      gll16(&A[(size_t)(m0 + row) * K + k0 + seg * 8], &As[b][idx * 8]);
      gll16(&Bm[(size_t)(n0 + row) * K + k0 + seg * 8], &Bs[b][idx * 8]);
    }
  };

  f32x4 acc[4][4] = {};
  stage(0, 0);
  int cur = 0;
  const int NT = K / 64;
  for (int kt = 0; kt < NT; ++kt, cur ^= 1) {
    __syncthreads();                       // drains staging kt; fences compiler
    if (kt + 1 < NT) stage((kt + 1) * 64, cur ^ 1);
    for (int kk = 0; kk < 64; kk += 32) {
      f16x8 af[4], bf[4];
      for (int a = 0; a < 4; ++a)
        af[a] = *(const f16x8*)&As[cur][(wr * 64 + a * 16 + l15) * 64 + kk + lg * 8];
      for (int b = 0; b < 4; ++b)
        bf[b] = *(const f16x8*)&Bs[cur][(wc * 64 + b * 16 + l15) * 64 + kk + lg * 8];
      for (int a = 0; a < 4; ++a)
        for (int b = 0; b < 4; ++b)
          acc[a][b] = __builtin_amdgcn_mfma_f32_16x16x32_f16(af[a], bf[b], acc[a][b], 0, 0, 0);
    }
  }
  for (int b = 0; b < 4; ++b) {
    int gcol = n0 + wc * 64 + b * 16 + l15;
    float bv = g.bias[gcol];
    for (int a = 0; a < 4; ++a) {
      int gr = m0 + wr * 64 + a * 16 + lg * 4;
      for (int r = 0; r < 4; ++r) {
        float vv = acc[a][b][r] + bv;
        if (g.oh) g.oh[(size_t)(gr + r) * N + gcol] = (f16)vv;
        else      g.of[(size_t)(gr + r) * N + gcol] = vv;
      }
    }
  }
}

// ---------------- vh [B*S, D] -> vhT [B,H,64,S] ----------------
__global__ void transpose_vh(const f16* __restrict__ vh, f16* __restrict__ vhT) {
  __shared__ f16 T[64 * 80];
  const int t = threadIdx.x;
  const int s0 = blockIdx.x * 64;
  const int bh = blockIdx.y, b = bh >> 4, h = bh & 15;
  for (int i = 0; i < 2; ++i) {
    int idx = i * 256 + t, row = idx >> 3, seg = idx & 7;
    f16x8 v = *(const f16x8*)&vh[(size_t)(b * NS + s0 + row) * ND + h * 64 + seg * 8];
    *(f16x8*)&T[row * 80 + seg * 8] = v;
  }
  __syncthreads();
  for (int i = 0; i < 2; ++i) {
    int idx = i * 256 + t, d = idx >> 3, seg = idx & 7;
    f16x8 o;
    for (int j = 0; j < 8; ++j) o[j] = T[(seg * 8 + j) * 80 + d];
    *(f16x8*)&vhT[((size_t)bh * 64 + d) * NS + s0 + seg * 8] = o;
  }
}

// ---------------- attention: R14 + widened full-line s-stores ----------------
// 1024 blocks (32 bh x 32 q-blocks of 64 rows), 4 waves x 16 q-rows, 4 blocks/CU.
// s-store: f32x4/lane, 8 lanes = one full 32-col row chunk (128B) -> one instr
// covers 8 rows x 128B complete lines; 2 instrs per ph (was 4).
__launch_bounds__(256, 4)
__global__ void attn_kernel(const f16* __restrict__ qh, const f16* __restrict__ kh,
                            const f16* __restrict__ vhT, f16* __restrict__ attnW,
                            float* __restrict__ sOut) {
  __shared__ f16 Ks[2][64 * 64];   // 16 KB
  __shared__ f16 Vts[2][64 * 64];  // 16 KB
  __shared__ f16 Ps[64 * 36];      // 4.6 KB, wave-private 16-row stripes
  const int t = threadIdx.x, w = t >> 6, l = t & 63, l15 = l & 15, lg = l >> 4;
  const int bid = blockIdx.x;
  const int wg = (bid & 7) * 128 + (bid >> 3);     // bijective XCD swizzle (1024)
  const int bh = wg >> 5, qi = wg & 31;
  const int q0 = qi * 64;
  const int b = bh >> 4, h = bh & 15;
  const f16* Qb = qh + (size_t)(b * NS) * ND + h * 64;
  const f16* Kb = kh + (size_t)(b * NS) * ND + h * 64;
  const f16* Vb = vhT + (size_t)bh * 64 * NS;
  const int NT = NS / 64;

  const int wbase = q0 + w * 16;
  const int dkt  = wbase >> 6;
  const int dbb  = (wbase & 63) >> 4;
  const int dlg = l15 >> 2, dr = l15 & 3;
  const int sw = l15 & 7;

  auto stageK = [&](int kt, int bf) {
    for (int i = 0; i < 2; ++i) {
      int idx = i * 256 + t, row = idx >> 3, seg = idx & 7;
      gll16(&Kb[(size_t)(kt * 64 + row) * ND + (seg ^ (row & 7)) * 8], &Ks[bf][idx * 8]);
    }
  };
  auto stageV = [&](int kt, int bf) {
    for (int i = 0; i < 2; ++i) {
      int idx = i * 256 + t, row = idx >> 3, seg = idx & 7;
      gll16(&Vb[(size_t)row * NS + kt * 64 + (seg ^ (row & 7)) * 8], &Vts[bf][idx * 8]);
    }
  };

  // Q fragments (B-operand): lane l15 = q-col
  f16x8 qf[2];
  qf[0] = *(const f16x8*)&Qb[(size_t)(wbase + l15) * ND + lg * 8];
  qf[1] = *(const f16x8*)&Qb[(size_t)(wbase + l15) * ND + 32 + lg * 8];

  float Zp = 0.f, Dp = 0.f;

  // ---- pass 1: Z and diag sums (top-sync dbuf) ----
  stageK(0, 0);
  int cur = 0;
  for (int kt = 0; kt < NT; ++kt, cur ^= 1) {
    __syncthreads();
    if (kt + 1 < NT) stageK(kt + 1, cur ^ 1);
    f32x4 accs[4] = {};
#pragma unroll
    for (int kkI = 0; kkI < 2; ++kkI)
#pragma unroll
      for (int bb = 0; bb < 4; ++bb) {
        f16x8 kf_ = *(const f16x8*)&Ks[cur][(bb * 16 + l15) * 64 + ((kkI * 4 + lg) ^ sw) * 8];
        accs[bb] = __builtin_amdgcn_mfma_f32_16x16x32_f16(kf_, qf[kkI], accs[bb], 0, 0, 0);
      }
#pragma unroll
    for (int bb = 0; bb < 4; ++bb) {
      float e0 = EXP2F(accs[bb][0] * SCL);
      float e1 = EXP2F(accs[bb][1] * SCL);
      float e2 = EXP2F(accs[bb][2] * SCL);
      float e3 = EXP2F(accs[bb][3] * SCL);
      Zp += (e0 + e1) + (e2 + e3);
      if (kt == dkt && bb == dbb && lg == dlg)
        Dp += dr == 0 ? e0 : dr == 1 ? e1 : dr == 2 ? e2 : e3;
    }
  }

  // reduce across the 4 lg groups (same l15 = same q-row)
  float z = Zp, d = Dp;
  z += __shfl_xor(z, 16, 64); z += __shfl_xor(z, 32, 64);
  d += __shfl_xor(d, 16, 64); d += __shfl_xor(d, 32, 64);
  const float rden = 1.f / (z - d + EPSF * z);

  // ---- pass 2: scores -> Ps (f16) -> PV + full-line s-store (top-sync dbuf) ----
  f32x4 acco[4] = {};
  float* sRow = sOut + (size_t)bh * NS * NS;
  const int srow8 = l >> 3;            // 0..7: row-group for the coalesced store
  const int sc8   = (l & 7) * 4;       // f32 col within the 32-col chunk
  stageK(0, 0);
  stageV(0, 0);
  cur = 0;
  for (int kt = 0; kt < NT; ++kt, cur ^= 1) {
    __syncthreads();
    if (kt + 1 < NT) { stageK(kt + 1, cur ^ 1); stageV(kt + 1, cur ^ 1); }
    f32x4 accs[4] = {};
#pragma unroll
    for (int kkI = 0; kkI < 2; ++kkI)
#pragma unroll
      for (int bb = 0; bb < 4; ++bb) {
        f16x8 kf_ = *(const f16x8*)&Ks[cur][(bb * 16 + l15) * 64 + ((kkI * 4 + lg) ^ sw) * 8];
        accs[bb] = __builtin_amdgcn_mfma_f32_16x16x32_f16(kf_, qf[kkI], accs[bb], 0, 0, 0);
      }
    // two k-chunks of 32; Ps reused (same-wave LDS ops are in-order)
#pragma unroll
    for (int ph = 0; ph < 2; ++ph) {
#pragma unroll
      for (int bbi = 0; bbi < 2; ++bbi) {
        const int bb = ph * 2 + bbi;
        float p0 = EXP2F(accs[bb][0] * SCL) * rden;
        float p1 = EXP2F(accs[bb][1] * SCL) * rden;
        float p2 = EXP2F(accs[bb][2] * SCL) * rden;
        float p3 = EXP2F(accs[bb][3] * SCL) * rden;
        if (kt == dkt && bb == dbb && lg == dlg) {
          if (dr == 0) p0 = 0.f;
          if (dr == 1) p1 = 0.f;
          if (dr == 2) p2 = 0.f;
          if (dr == 3) p3 = 0.f;
        }
        f16x4 phk = {(f16)p0, (f16)p1, (f16)p2, (f16)p3};
        *(f16x4*)&Ps[(w * 16 + l15) * 36 + bbi * 16 + lg * 4] = phk;
      }
      f16x8 pa = *(const f16x8*)&Ps[(w * 16 + l15) * 36 + lg * 8];
#pragma unroll
      for (int c = 0; c < 4; ++c) {
        f16x8 vf_ = *(const f16x8*)&Vts[cur][(c * 16 + l15) * 64 + ((ph * 4 + lg) ^ sw) * 8];
        acco[c] = __builtin_amdgcn_mfma_f32_16x16x32_f16(pa, vf_, acco[c], 0, 0, 0);
      }
      // full-line s-store: 8 lanes x f32x4 = one 128B row chunk; 8 rows/instr.
#pragma unroll
      for (int i = 0; i < 2; ++i) {
        const int lrow = i * 8 + srow8;                 // 0..15 within stripe
        f16x4 pv4 = *(const f16x4*)&Ps[(w * 16 + lrow) * 36 + sc8];
        f32x4 st = {(float)pv4[0], (float)pv4[1], (float)pv4[2], (float)pv4[3]};
        __builtin_nontemporal_store(st,
            (f32x4*)&sRow[(size_t)(wbase + lrow) * NS + kt * 64 + ph * 32 + sc8]);
      }
    }
  }

  // epilogue: acco col=l15=d, row=lg*4+r=q-offset
#pragma unroll
  for (int c = 0; c < 4; ++c)
#pragma unroll
    for (int r = 0; r < 4; ++r)
      attnW[(size_t)(b * NS + wbase + lg * 4 + r) * ND + h * 64 + c * 16 + l15] =
          (f16)acco[c][r];
}

extern "C" void kernel_launch(void* const* d_in, const int* in_sizes, int n_in,
                              void* d_out, int out_size, void* d_ws, size_t ws_size,
                              hipStream_t stream) {
  const float* q  = (const float*)d_in[0];
  const float* k  = (const float*)d_in[1];
  const float* v  = (const float*)d_in[2];
  const float* Wq = (const float*)d_in[3];
  const float* bq = (const float*)d_in[4];
  const float* Wk = (const float*)d_in[5];
  const float* bk = (const float*)d_in[6];
  const float* Wv = (const float*)d_in[7];
  const float* bv = (const float*)d_in[8];
  const float* Wo = (const float*)d_in[9];
  const float* bo = (const float*)d_in[10];

  float* out  = (float*)d_out;
  float* sOut = out + (size_t)NB * NS * ND;   // s region, 134.2M floats

  const size_t EL = (size_t)NB * NS * ND;     // 4,194,304
  const size_t WL = (size_t)ND * ND;          // 1,048,576

  // fp16 input copies in the (not-yet-written) s region of d_out
  f16* sc  = (f16*)sOut;
  f16 *qf  = sc,            *kf  = sc + EL,      *vf  = sc + 2 * EL;
  f16 *Wq6 = sc + 3 * EL,   *Wk6 = Wq6 + WL,     *Wv6 = Wk6 + WL;

  // d_ws: qh, kh, vh, vhT, attn (8 MB each) + Wo16 (2 MB)
  f16* wsh = (f16*)d_ws;
  f16 *qhW  = wsh,          *khW  = wsh + EL,    *vhW = wsh + 2 * EL;
  f16 *vhT  = wsh + 3 * EL, *attn = wsh + 4 * EL;
  f16 *Wo6  = wsh + 5 * EL;

  CvtArgs ca;
  ca.src[0]=q;  ca.dst[0]=qf;  ca.n8[0]=(int)(EL/8);
  ca.src[1]=k;  ca.dst[1]=kf;  ca.n8[1]=(int)(EL/8);
  ca.src[2]=v;  ca.dst[2]=vf;  ca.n8[2]=(int)(EL/8);
  ca.src[3]=Wq; ca.dst[3]=Wq6; ca.n8[3]=(int)(WL/8);
  ca.src[4]=Wk; ca.dst[4]=Wk6; ca.n8[4]=(int)(WL/8);
  ca.src[5]=Wv; ca.dst[5]=Wv6; ca.n8[5]=(int)(WL/8);
  ca.src[6]=Wo; ca.dst[6]=Wo6; ca.n8[6]=(int)(WL/8);
  cvt_multi<<<dim3(2048, 7), 256, 0, stream>>>(ca);

  // fused QKV projections (768 blocks, XCD-swizzled in-kernel)
  GemmBatch gq;
  gq.op[0] = { qf, Wq6, bq, qhW, nullptr };
  gq.op[1] = { kf, Wk6, bk, khW, nullptr };
  gq.op[2] = { vf, Wv6, bv, vhW, nullptr };
  gemm_nt_f16<<<dim3(32, 8, 3), 256, 0, stream>>>(gq, NB * NS, ND, ND);

  // vh -> vhT [B,H,64,S]
  transpose_vh<<<dim3(32, 32), 256, 0, stream>>>(vhW, vhT);

  // attention (writes s region + attn), two passes in-kernel
  attn_kernel<<<dim3(1024), 256, 0, stream>>>(qhW, khW, vhT, attn, sOut);

  // output projection (256 blocks, XCD-swizzled in-kernel)
  GemmBatch go;
  go.op[0] = { attn, Wo6, bo, nullptr, out };
  go.op[1] = go.op[0];
  go.op[2] = go.op[0];
  gemm_nt_f16<<<dim3(32, 8, 1), 256, 0, stream>>>(go, NB * NS, ND, ND);
}

// Round 16
// 240.849 us; speedup vs baseline: 1.0403x; 1.0403x over previous
//
#include <hip/hip_runtime.h>
#include <math.h>

typedef _Float16 f16;
typedef _Float16 f16x2 __attribute__((ext_vector_type(2)));
typedef _Float16 f16x4 __attribute__((ext_vector_type(4)));
typedef _Float16 f16x8 __attribute__((ext_vector_type(8)));
typedef float f32x2 __attribute__((ext_vector_type(2)));
typedef float f32x4 __attribute__((ext_vector_type(4)));

#define NB   2
#define NS   2048
#define ND   1024
#define NH   16
#define NHD  64
#define EPSF 1e-6f
#define SCL  0.18033688011110793f   // 0.125 * log2(e)
#define EXP2F(x) __builtin_exp2f(x) // lowers to v_exp_f32 (HW is 2^x)

__device__ __forceinline__ void gll16(const void* g, void* l) {
  __builtin_amdgcn_global_load_lds(
      (const __attribute__((address_space(1))) void*)g,
      (__attribute__((address_space(3))) void*)l, 16, 0, 0);
}

// ---------------- fused fp32 -> fp16 convert: 7 tensors, one launch ----------------
struct CvtArgs { const float* src[7]; f16* dst[7]; int n8[7]; };

__global__ void cvt_multi(CvtArgs a) {
  const int ti = blockIdx.y;
  const int i = blockIdx.x * blockDim.x + threadIdx.x;
  if (i >= a.n8[ti]) return;
  const float4* s4 = (const float4*)a.src[ti] + (size_t)i * 2;
  float4 x = s4[0], y = s4[1];
  f16x8 o;
  o[0]=(f16)x.x; o[1]=(f16)x.y; o[2]=(f16)x.z; o[3]=(f16)x.w;
  o[4]=(f16)y.x; o[5]=(f16)y.y; o[6]=(f16)y.z; o[7]=(f16)y.w;
  ((f16x8*)a.dst[ti])[i] = o;
}

// ---------------- GEMM: C[M][N] = A[M][K] * B[N][K]^T + bias ----------------
// 128x128 tile, BK=64, 4 waves, top-sync dbuf. Output paths: f16 row-major (oh),
// f32 row-major (of), or f16 TRANSPOSED per-head [B,H,64,S] (vt - V projection:
// the 4 consecutive gr rows per lane are contiguous along vhT's s-axis).
struct GemmOps { const f16* A; const f16* Bw; const float* bias; f16* oh; float* of; f16* vt; };
struct GemmBatch { GemmOps op[3]; };

__launch_bounds__(256, 2)
__global__ void gemm_nt_f16(GemmBatch gb, int M, int N, int K) {
  __shared__ f16 As[2][128 * 64];
  __shared__ f16 Bs[2][128 * 64];
  const GemmOps g = gb.op[blockIdx.z];
  const int t = threadIdx.x;
  const int w = t >> 6, l = t & 63, l15 = l & 15, lg = l >> 4;
  const int wr = w >> 1, wc = w & 1;
  const int m0 = blockIdx.x * 128, n0 = blockIdx.y * 128;
  const f16* A = g.A;
  const f16* Bm = g.Bw;

  auto stage = [&](int k0, int b) {
    for (int i = 0; i < 4; ++i) {
      int idx = i * 256 + t;
      int row = idx >> 3, seg = idx & 7;
      gll16(&A[(size_t)(m0 + row) * K + k0 + seg * 8], &As[b][idx * 8]);
      gll16(&Bm[(size_t)(n0 + row) * K + k0 + seg * 8], &Bs[b][idx * 8]);
    }
  };

  f32x4 acc[4][4] = {};
  stage(0, 0);
  int cur = 0;
  const int NT = K / 64;
  for (int kt = 0; kt < NT; ++kt, cur ^= 1) {
    __syncthreads();                       // drains staging kt; fences compiler
    if (kt + 1 < NT) stage((kt + 1) * 64, cur ^ 1);
    for (int kk = 0; kk < 64; kk += 32) {
      f16x8 af[4], bf[4];
      for (int a = 0; a < 4; ++a)
        af[a] = *(const f16x8*)&As[cur][(wr * 64 + a * 16 + l15) * 64 + kk + lg * 8];
      for (int b = 0; b < 4; ++b)
        bf[b] = *(const f16x8*)&Bs[cur][(wc * 64 + b * 16 + l15) * 64 + kk + lg * 8];
      for (int a = 0; a < 4; ++a)
        for (int b = 0; b < 4; ++b)
          acc[a][b] = __builtin_amdgcn_mfma_f32_16x16x32_f16(af[a], bf[b], acc[a][b], 0, 0, 0);
    }
  }
  for (int b = 0; b < 4; ++b) {
    int gcol = n0 + wc * 64 + b * 16 + l15;
    float bv = g.bias[gcol];
    if (g.vt) {
      // transposed V store: vhT[((b_*16+h)*64+d)*NS + s], 4 consecutive s per lane
      const int hh = gcol >> 6, dd = gcol & 63;
      for (int a = 0; a < 4; ++a) {
        int gr = m0 + wr * 64 + a * 16 + lg * 4;
        const int b_ = gr >> 11, s = gr & 2047;
        f16x4 pk;
        for (int r = 0; r < 4; ++r) pk[r] = (f16)(acc[a][b][r] + bv);
        *(f16x4*)&g.vt[((size_t)(b_ * 16 + hh) * 64 + dd) * NS + s] = pk;
      }
    } else {
      for (int a = 0; a < 4; ++a) {
        int gr = m0 + wr * 64 + a * 16 + lg * 4;
        for (int r = 0; r < 4; ++r) {
          float vv = acc[a][b][r] + bv;
          if (g.oh) g.oh[(size_t)(gr + r) * N + gcol] = (f16)vv;
          else      g.of[(size_t)(gr + r) * N + gcol] = vv;
        }
      }
    }
  }
}

// ---------------- attention: R14 structure (best: 244.7 us) ----------------
// 1024 blocks (32 bh x 32 q-blocks of 64 rows), 4 waves x 16 q-rows, 4 blocks/CU.
// Full-line coalesced s-stores: f32x2/lane via Ps readback = 4 rows x 128B
// complete lines per instr (the R14 win: kills partial-line write amplification).
__launch_bounds__(256, 4)
__global__ void attn_kernel(const f16* __restrict__ qh, const f16* __restrict__ kh,
                            const f16* __restrict__ vhT, f16* __restrict__ attnW,
                            float* __restrict__ sOut) {
  __shared__ f16 Ks[2][64 * 64];   // 16 KB
  __shared__ f16 Vts[2][64 * 64];  // 16 KB
  __shared__ f16 Ps[64 * 36];      // 4.6 KB, wave-private 16-row stripes
  const int t = threadIdx.x, w = t >> 6, l = t & 63, l15 = l & 15, lg = l >> 4;
  const int bid = blockIdx.x;
  const int wg = (bid & 7) * 128 + (bid >> 3);     // bijective XCD swizzle (1024)
  const int bh = wg >> 5, qi = wg & 31;
  const int q0 = qi * 64;
  const int b = bh >> 4, h = bh & 15;
  const f16* Qb = qh + (size_t)(b * NS) * ND + h * 64;
  const f16* Kb = kh + (size_t)(b * NS) * ND + h * 64;
  const f16* Vb = vhT + (size_t)bh * 64 * NS;
  const int NT = NS / 64;

  const int wbase = q0 + w * 16;
  const int dkt  = wbase >> 6;
  const int dbb  = (wbase & 63) >> 4;
  const int dlg = l15 >> 2, dr = l15 & 3;
  const int sw = l15 & 7;

  auto stageK = [&](int kt, int bf) {
    for (int i = 0; i < 2; ++i) {
      int idx = i * 256 + t, row = idx >> 3, seg = idx & 7;
      gll16(&Kb[(size_t)(kt * 64 + row) * ND + (seg ^ (row & 7)) * 8], &Ks[bf][idx * 8]);
    }
  };
  auto stageV = [&](int kt, int bf) {
    for (int i = 0; i < 2; ++i) {
      int idx = i * 256 + t, row = idx >> 3, seg = idx & 7;
      gll16(&Vb[(size_t)row * NS + kt * 64 + (seg ^ (row & 7)) * 8], &Vts[bf][idx * 8]);
    }
  };

  // Q fragments (B-operand): lane l15 = q-col
  f16x8 qf[2];
  qf[0] = *(const f16x8*)&Qb[(size_t)(wbase + l15) * ND + lg * 8];
  qf[1] = *(const f16x8*)&Qb[(size_t)(wbase + l15) * ND + 32 + lg * 8];

  float Zp = 0.f, Dp = 0.f;

  // ---- pass 1: Z and diag sums (top-sync dbuf) ----
  stageK(0, 0);
  int cur = 0;
  for (int kt = 0; kt < NT; ++kt, cur ^= 1) {
    __syncthreads();
    if (kt + 1 < NT) stageK(kt + 1, cur ^ 1);
    f32x4 accs[4] = {};
#pragma unroll
    for (int kkI = 0; kkI < 2; ++kkI)
#pragma unroll
      for (int bb = 0; bb < 4; ++bb) {
        f16x8 kf_ = *(const f16x8*)&Ks[cur][(bb * 16 + l15) * 64 + ((kkI * 4 + lg) ^ sw) * 8];
        accs[bb] = __builtin_amdgcn_mfma_f32_16x16x32_f16(kf_, qf[kkI], accs[bb], 0, 0, 0);
      }
#pragma unroll
    for (int bb = 0; bb < 4; ++bb) {
      float e0 = EXP2F(accs[bb][0] * SCL);
      float e1 = EXP2F(accs[bb][1] * SCL);
      float e2 = EXP2F(accs[bb][2] * SCL);
      float e3 = EXP2F(accs[bb][3] * SCL);
      Zp += (e0 + e1) + (e2 + e3);
      if (kt == dkt && bb == dbb && lg == dlg)
        Dp += dr == 0 ? e0 : dr == 1 ? e1 : dr == 2 ? e2 : e3;
    }
  }

  // reduce across the 4 lg groups (same l15 = same q-row)
  float z = Zp, d = Dp;
  z += __shfl_xor(z, 16, 64); z += __shfl_xor(z, 32, 64);
  d += __shfl_xor(d, 16, 64); d += __shfl_xor(d, 32, 64);
  const float rden = 1.f / (z - d + EPSF * z);

  // ---- pass 2: scores -> Ps (f16) -> PV + full-line s-store (top-sync dbuf) ----
  f32x4 acco[4] = {};
  float* sRow = sOut + (size_t)bh * NS * NS;
  const int srow4 = l >> 4;            // 0..3: row-group for the coalesced store
  const int scol  = (l & 15) * 2;      // f16-pair index within the 32-col chunk
  stageK(0, 0);
  stageV(0, 0);
  cur = 0;
  for (int kt = 0; kt < NT; ++kt, cur ^= 1) {
    __syncthreads();
    if (kt + 1 < NT) { stageK(kt + 1, cur ^ 1); stageV(kt + 1, cur ^ 1); }
    f32x4 accs[4] = {};
#pragma unroll
    for (int kkI = 0; kkI < 2; ++kkI)
#pragma unroll
      for (int bb = 0; bb < 4; ++bb) {
        f16x8 kf_ = *(const f16x8*)&Ks[cur][(bb * 16 + l15) * 64 + ((kkI * 4 + lg) ^ sw) * 8];
        accs[bb] = __builtin_amdgcn_mfma_f32_16x16x32_f16(kf_, qf[kkI], accs[bb], 0, 0, 0);
      }
    // two k-chunks of 32; Ps reused (same-wave LDS ops are in-order)
#pragma unroll
    for (int ph = 0; ph < 2; ++ph) {
#pragma unroll
      for (int bbi = 0; bbi < 2; ++bbi) {
        const int bb = ph * 2 + bbi;
        float p0 = EXP2F(accs[bb][0] * SCL) * rden;
        float p1 = EXP2F(accs[bb][1] * SCL) * rden;
        float p2 = EXP2F(accs[bb][2] * SCL) * rden;
        float p3 = EXP2F(accs[bb][3] * SCL) * rden;
        if (kt == dkt && bb == dbb && lg == dlg) {
          if (dr == 0) p0 = 0.f;
          if (dr == 1) p1 = 0.f;
          if (dr == 2) p2 = 0.f;
          if (dr == 3) p3 = 0.f;
        }
        f16x4 phk = {(f16)p0, (f16)p1, (f16)p2, (f16)p3};
        *(f16x4*)&Ps[(w * 16 + l15) * 36 + bbi * 16 + lg * 4] = phk;
      }
      f16x8 pa = *(const f16x8*)&Ps[(w * 16 + l15) * 36 + lg * 8];
#pragma unroll
      for (int c = 0; c < 4; ++c) {
        f16x8 vf_ = *(const f16x8*)&Vts[cur][(c * 16 + l15) * 64 + ((ph * 4 + lg) ^ sw) * 8];
        acco[c] = __builtin_amdgcn_mfma_f32_16x16x32_f16(pa, vf_, acco[c], 0, 0, 0);
      }
      // full-line s-store: lane-major readback of Ps (diag-zeroed, normalized),
      // f32x2/lane -> each instr = 4 rows x 128B aligned = 4 complete lines.
#pragma unroll
      for (int i = 0; i < 4; ++i) {
        const int lrow = i * 4 + srow4;                 // 0..15 within stripe
        f16x2 pv2 = *(const f16x2*)&Ps[(w * 16 + lrow) * 36 + scol];
        f32x2 st = {(float)pv2[0], (float)pv2[1]};
        __builtin_nontemporal_store(st,
            (f32x2*)&sRow[(size_t)(wbase + lrow) * NS + kt * 64 + ph * 32 + scol]);
      }
    }
  }

  // epilogue: acco col=l15=d, row=lg*4+r=q-offset
#pragma unroll
  for (int c = 0; c < 4; ++c)
#pragma unroll
    for (int r = 0; r < 4; ++r)
      attnW[(size_t)(b * NS + wbase + lg * 4 + r) * ND + h * 64 + c * 16 + l15] =
          (f16)acco[c][r];
}

extern "C" void kernel_launch(void* const* d_in, const int* in_sizes, int n_in,
                              void* d_out, int out_size, void* d_ws, size_t ws_size,
                              hipStream_t stream) {
  const float* q  = (const float*)d_in[0];
  const float* k  = (const float*)d_in[1];
  const float* v  = (const float*)d_in[2];
  const float* Wq = (const float*)d_in[3];
  const float* bq = (const float*)d_in[4];
  const float* Wk = (const float*)d_in[5];
  const float* bk = (const float*)d_in[6];
  const float* Wv = (const float*)d_in[7];
  const float* bv = (const float*)d_in[8];
  const float* Wo = (const float*)d_in[9];
  const float* bo = (const float*)d_in[10];

  float* out  = (float*)d_out;
  float* sOut = out + (size_t)NB * NS * ND;   // s region, 134.2M floats

  const size_t EL = (size_t)NB * NS * ND;     // 4,194,304
  const size_t WL = (size_t)ND * ND;          // 1,048,576

  // fp16 input copies in the (not-yet-written) s region of d_out
  f16* sc  = (f16*)sOut;
  f16 *qf  = sc,            *kf  = sc + EL,      *vf  = sc + 2 * EL;
  f16 *Wq6 = sc + 3 * EL,   *Wk6 = Wq6 + WL,     *Wv6 = Wk6 + WL;

  // d_ws: qh, kh, vhT, attn (8 MB each) + Wo16 (2 MB)
  f16* wsh = (f16*)d_ws;
  f16 *qhW  = wsh,          *khW  = wsh + EL;
  f16 *vhT  = wsh + 3 * EL, *attn = wsh + 4 * EL;
  f16 *Wo6  = wsh + 5 * EL;

  CvtArgs ca;
  ca.src[0]=q;  ca.dst[0]=qf;  ca.n8[0]=(int)(EL/8);
  ca.src[1]=k;  ca.dst[1]=kf;  ca.n8[1]=(int)(EL/8);
  ca.src[2]=v;  ca.dst[2]=vf;  ca.n8[2]=(int)(EL/8);
  ca.src[3]=Wq; ca.dst[3]=Wq6; ca.n8[3]=(int)(WL/8);
  ca.src[4]=Wk; ca.dst[4]=Wk6; ca.n8[4]=(int)(WL/8);
  ca.src[5]=Wv; ca.dst[5]=Wv6; ca.n8[5]=(int)(WL/8);
  ca.src[6]=Wo; ca.dst[6]=Wo6; ca.n8[6]=(int)(WL/8);
  cvt_multi<<<dim3(2048, 7), 256, 0, stream>>>(ca);

  // fused QKV projections; V writes TRANSPOSED [B,H,64,S] directly (no
  // separate transpose kernel: saves a launch + 16 MB of traffic)
  GemmBatch gq;
  gq.op[0] = { qf, Wq6, bq, qhW,    nullptr, nullptr };
  gq.op[1] = { kf, Wk6, bk, khW,    nullptr, nullptr };
  gq.op[2] = { vf, Wv6, bv, nullptr, nullptr, vhT    };
  gemm_nt_f16<<<dim3(32, 8, 3), 256, 0, stream>>>(gq, NB * NS, ND, ND);

  // attention (writes s region + attn), two passes in-kernel
  attn_kernel<<<dim3(1024), 256, 0, stream>>>(qhW, khW, vhT, attn, sOut);

  // output projection
  GemmBatch go;
  go.op[0] = { attn, Wo6, bo, nullptr, out, nullptr };
  go.op[1] = go.op[0];
  go.op[2] = go.op[0];
  gemm_nt_f16<<<dim3(32, 8, 1), 256, 0, stream>>>(go, NB * NS, ND, ND);
}

// Round 17
// 238.021 us; speedup vs baseline: 1.0526x; 1.0119x over previous
//
#include <hip/hip_runtime.h>
#include <math.h>

typedef _Float16 f16;
typedef _Float16 f16x2 __attribute__((ext_vector_type(2)));
typedef _Float16 f16x4 __attribute__((ext_vector_type(4)));
typedef _Float16 f16x8 __attribute__((ext_vector_type(8)));
typedef float f32x2 __attribute__((ext_vector_type(2)));
typedef float f32x4 __attribute__((ext_vector_type(4)));

#define NB   2
#define NS   2048
#define ND   1024
#define NH   16
#define NHD  64
#define EPSF 1e-6f
#define SCL  0.18033688011110793f   // 0.125 * log2(e)
#define EXP2F(x) __builtin_exp2f(x) // lowers to v_exp_f32 (HW is 2^x)

__device__ __forceinline__ void gll16(const void* g, void* l) {
  __builtin_amdgcn_global_load_lds(
      (const __attribute__((address_space(1))) void*)g,
      (__attribute__((address_space(3))) void*)l, 16, 0, 0);
}

// ---------------- fused fp32 -> fp16 convert: 7 tensors, one launch ----------------
struct CvtArgs { const float* src[7]; f16* dst[7]; int n8[7]; };

__global__ void cvt_multi(CvtArgs a) {
  const int ti = blockIdx.y;
  const int i = blockIdx.x * blockDim.x + threadIdx.x;
  if (i >= a.n8[ti]) return;
  const float4* s4 = (const float4*)a.src[ti] + (size_t)i * 2;
  float4 x = s4[0], y = s4[1];
  f16x8 o;
  o[0]=(f16)x.x; o[1]=(f16)x.y; o[2]=(f16)x.z; o[3]=(f16)x.w;
  o[4]=(f16)y.x; o[5]=(f16)y.y; o[6]=(f16)y.z; o[7]=(f16)y.w;
  ((f16x8*)a.dst[ti])[i] = o;
}

// ---------------- GEMM: C[M][N] = A[M][K] * B[N][K]^T + bias ----------------
// 128x128 tile, BK=64, 4 waves, top-sync dbuf. Output paths: f16 row-major (oh),
// f32 row-major (of), or f16 TRANSPOSED per-head [B,H,64,S] (vt - V projection).
struct GemmOps { const f16* A; const f16* Bw; const float* bias; f16* oh; float* of; f16* vt; };
struct GemmBatch { GemmOps op[3]; };

__launch_bounds__(256, 2)
__global__ void gemm_nt_f16(GemmBatch gb, int M, int N, int K) {
  __shared__ f16 As[2][128 * 64];
  __shared__ f16 Bs[2][128 * 64];
  const GemmOps g = gb.op[blockIdx.z];
  const int t = threadIdx.x;
  const int w = t >> 6, l = t & 63, l15 = l & 15, lg = l >> 4;
  const int wr = w >> 1, wc = w & 1;
  const int m0 = blockIdx.x * 128, n0 = blockIdx.y * 128;
  const f16* A = g.A;
  const f16* Bm = g.Bw;

  auto stage = [&](int k0, int b) {
    for (int i = 0; i < 4; ++i) {
      int idx = i * 256 + t;
      int row = idx >> 3, seg = idx & 7;
      gll16(&A[(size_t)(m0 + row) * K + k0 + seg * 8], &As[b][idx * 8]);
      gll16(&Bm[(size_t)(n0 + row) * K + k0 + seg * 8], &Bs[b][idx * 8]);
    }
  };

  f32x4 acc[4][4] = {};
  stage(0, 0);
  int cur = 0;
  const int NT = K / 64;
  for (int kt = 0; kt < NT; ++kt, cur ^= 1) {
    __syncthreads();                       // drains staging kt; fences compiler
    if (kt + 1 < NT) stage((kt + 1) * 64, cur ^ 1);
    for (int kk = 0; kk < 64; kk += 32) {
      f16x8 af[4], bf[4];
      for (int a = 0; a < 4; ++a)
        af[a] = *(const f16x8*)&As[cur][(wr * 64 + a * 16 + l15) * 64 + kk + lg * 8];
      for (int b = 0; b < 4; ++b)
        bf[b] = *(const f16x8*)&Bs[cur][(wc * 64 + b * 16 + l15) * 64 + kk + lg * 8];
      for (int a = 0; a < 4; ++a)
        for (int b = 0; b < 4; ++b)
          acc[a][b] = __builtin_amdgcn_mfma_f32_16x16x32_f16(af[a], bf[b], acc[a][b], 0, 0, 0);
    }
  }
  for (int b = 0; b < 4; ++b) {
    int gcol = n0 + wc * 64 + b * 16 + l15;
    float bv = g.bias[gcol];
    if (g.vt) {
      // transposed V store: vhT[((b_*16+h)*64+d)*NS + s], 4 consecutive s per lane
      const int hh = gcol >> 6, dd = gcol & 63;
      for (int a = 0; a < 4; ++a) {
        int gr = m0 + wr * 64 + a * 16 + lg * 4;
        const int b_ = gr >> 11, s = gr & 2047;
        f16x4 pk;
        for (int r = 0; r < 4; ++r) pk[r] = (f16)(acc[a][b][r] + bv);
        *(f16x4*)&g.vt[((size_t)(b_ * 16 + hh) * 64 + dd) * NS + s] = pk;
      }
    } else {
      for (int a = 0; a < 4; ++a) {
        int gr = m0 + wr * 64 + a * 16 + lg * 4;
        for (int r = 0; r < 4; ++r) {
          float vv = acc[a][b][r] + bv;
          if (g.oh) g.oh[(size_t)(gr + r) * N + gcol] = (f16)vv;
          else      g.of[(size_t)(gr + r) * N + gcol] = vv;
        }
      }
    }
  }
}

// ---------------- attention: R16 + one-tile-deferred s-stores ----------------
// 1024 blocks (32 bh x 32 q-blocks of 64 rows), 4 waves x 16 q-rows, 4 blocks/CU.
// Ps enlarged to 64x64 (XOR-swizzled, col ^= (row&7)<<3) so tile kt's normalized
// P survives into kt+1: the 8 NT s-stores for kt are issued right AFTER sync
// kt+1 and drained at sync kt+2 -> a full tile (~1700cyc) to retire, removing
// the store-ack residue from every barrier drain. LDS = 16+16+8 = 40 KB.
__launch_bounds__(256, 4)
__global__ void attn_kernel(const f16* __restrict__ qh, const f16* __restrict__ kh,
                            const f16* __restrict__ vhT, f16* __restrict__ attnW,
                            float* __restrict__ sOut) {
  __shared__ f16 Ks[2][64 * 64];   // 16 KB
  __shared__ f16 Vts[2][64 * 64];  // 16 KB
  __shared__ f16 Ps[64 * 64];      // 8 KB, wave-private 16-row stripes, swizzled
  const int t = threadIdx.x, w = t >> 6, l = t & 63, l15 = l & 15, lg = l >> 4;
  const int bid = blockIdx.x;
  const int wg = (bid & 7) * 128 + (bid >> 3);     // bijective XCD swizzle (1024)
  const int bh = wg >> 5, qi = wg & 31;
  const int q0 = qi * 64;
  const int b = bh >> 4, h = bh & 15;
  const f16* Qb = qh + (size_t)(b * NS) * ND + h * 64;
  const f16* Kb = kh + (size_t)(b * NS) * ND + h * 64;
  const f16* Vb = vhT + (size_t)bh * 64 * NS;
  const int NT = NS / 64;

  const int wbase = q0 + w * 16;
  const int dkt  = wbase >> 6;
  const int dbb  = (wbase & 63) >> 4;
  const int dlg = l15 >> 2, dr = l15 & 3;
  const int sw = l15 & 7;

  auto stageK = [&](int kt, int bf) {
    for (int i = 0; i < 2; ++i) {
      int idx = i * 256 + t, row = idx >> 3, seg = idx & 7;
      gll16(&Kb[(size_t)(kt * 64 + row) * ND + (seg ^ (row & 7)) * 8], &Ks[bf][idx * 8]);
    }
  };
  auto stageV = [&](int kt, int bf) {
    for (int i = 0; i < 2; ++i) {
      int idx = i * 256 + t, row = idx >> 3, seg = idx & 7;
      gll16(&Vb[(size_t)row * NS + kt * 64 + (seg ^ (row & 7)) * 8], &Vts[bf][idx * 8]);
    }
  };

  // Q fragments (B-operand): lane l15 = q-col
  f16x8 qf[2];
  qf[0] = *(const f16x8*)&Qb[(size_t)(wbase + l15) * ND + lg * 8];
  qf[1] = *(const f16x8*)&Qb[(size_t)(wbase + l15) * ND + 32 + lg * 8];

  float Zp = 0.f, Dp = 0.f;

  // ---- pass 1: Z and diag sums (top-sync dbuf) ----
  stageK(0, 0);
  int cur = 0;
  for (int kt = 0; kt < NT; ++kt, cur ^= 1) {
    __syncthreads();
    if (kt + 1 < NT) stageK(kt + 1, cur ^ 1);
    f32x4 accs[4] = {};
#pragma unroll
    for (int kkI = 0; kkI < 2; ++kkI)
#pragma unroll
      for (int bb = 0; bb < 4; ++bb) {
        f16x8 kf_ = *(const f16x8*)&Ks[cur][(bb * 16 + l15) * 64 + ((kkI * 4 + lg) ^ sw) * 8];
        accs[bb] = __builtin_amdgcn_mfma_f32_16x16x32_f16(kf_, qf[kkI], accs[bb], 0, 0, 0);
      }
#pragma unroll
    for (int bb = 0; bb < 4; ++bb) {
      float e0 = EXP2F(accs[bb][0] * SCL);
      float e1 = EXP2F(accs[bb][1] * SCL);
      float e2 = EXP2F(accs[bb][2] * SCL);
      float e3 = EXP2F(accs[bb][3] * SCL);
      Zp += (e0 + e1) + (e2 + e3);
      if (kt == dkt && bb == dbb && lg == dlg)
        Dp += dr == 0 ? e0 : dr == 1 ? e1 : dr == 2 ? e2 : e3;
    }
  }

  // reduce across the 4 lg groups (same l15 = same q-row)
  float z = Zp, d = Dp;
  z += __shfl_xor(z, 16, 64); z += __shfl_xor(z, 32, 64);
  d += __shfl_xor(d, 16, 64); d += __shfl_xor(d, 32, 64);
  const float rden = 1.f / (z - d + EPSF * z);

  // ---- pass 2: scores -> Ps (swizzled) -> PV; s-store deferred one tile ----
  f32x4 acco[4] = {};
  float* sRow = sOut + (size_t)bh * NS * NS;
  const int prow  = w * 16 + l15;       // this lane's Ps row (write/PV side)
  const int pswz  = (l15 & 7) << 3;     // col-swizzle for that row
  const int srow4 = l >> 4;             // 0..3: row-group for the coalesced store
  const int scol  = (l & 15) * 2;       // f16-pair index within a 32-col chunk
  stageK(0, 0);
  stageV(0, 0);
  cur = 0;
  for (int kt = 0; kt < NT; ++kt, cur ^= 1) {
    __syncthreads();
    if (kt + 1 < NT) { stageK(kt + 1, cur ^ 1); stageV(kt + 1, cur ^ 1); }
    // deferred flush of tile kt-1's s (Ps still holds it; overwritten below)
    if (kt) {
#pragma unroll
      for (int cc = 0; cc < 2; ++cc)
#pragma unroll
        for (int i = 0; i < 4; ++i) {
          const int lrow = i * 4 + srow4;             // 0..15 within stripe
          const int psw2 = (lrow & 7) << 3;
          f16x2 pv2 = *(const f16x2*)&Ps[(w * 16 + lrow) * 64 + ((cc * 32 + scol) ^ psw2)];
          f32x2 st = {(float)pv2[0], (float)pv2[1]};
          __builtin_nontemporal_store(st,
              (f32x2*)&sRow[(size_t)(wbase + lrow) * NS + (kt - 1) * 64 + cc * 32 + scol]);
        }
    }
    f32x4 accs[4] = {};
#pragma unroll
    for (int kkI = 0; kkI < 2; ++kkI)
#pragma unroll
      for (int bb = 0; bb < 4; ++bb) {
        f16x8 kf_ = *(const f16x8*)&Ks[cur][(bb * 16 + l15) * 64 + ((kkI * 4 + lg) ^ sw) * 8];
        accs[bb] = __builtin_amdgcn_mfma_f32_16x16x32_f16(kf_, qf[kkI], accs[bb], 0, 0, 0);
      }
    // two k-chunks of 32; Ps 64-col (swizzled), same-wave LDS ops are in-order
#pragma unroll
    for (int ph = 0; ph < 2; ++ph) {
#pragma unroll
      for (int bbi = 0; bbi < 2; ++bbi) {
        const int bb = ph * 2 + bbi;
        float p0 = EXP2F(accs[bb][0] * SCL) * rden;
        float p1 = EXP2F(accs[bb][1] * SCL) * rden;
        float p2 = EXP2F(accs[bb][2] * SCL) * rden;
        float p3 = EXP2F(accs[bb][3] * SCL) * rden;
        if (kt == dkt && bb == dbb && lg == dlg) {
          if (dr == 0) p0 = 0.f;
          if (dr == 1) p1 = 0.f;
          if (dr == 2) p2 = 0.f;
          if (dr == 3) p3 = 0.f;
        }
        f16x4 phk = {(f16)p0, (f16)p1, (f16)p2, (f16)p3};
        *(f16x4*)&Ps[prow * 64 + ((ph * 32 + bbi * 16 + lg * 4) ^ pswz)] = phk;
      }
      f16x8 pa = *(const f16x8*)&Ps[prow * 64 + ((ph * 32 + lg * 8) ^ pswz)];
#pragma unroll
      for (int c = 0; c < 4; ++c) {
        f16x8 vf_ = *(const f16x8*)&Vts[cur][(c * 16 + l15) * 64 + ((ph * 4 + lg) ^ sw) * 8];
        acco[c] = __builtin_amdgcn_mfma_f32_16x16x32_f16(pa, vf_, acco[c], 0, 0, 0);
      }
    }
  }
  // final flush for tile NT-1 (Ps still valid after loop exit)
#pragma unroll
  for (int cc = 0; cc < 2; ++cc)
#pragma unroll
    for (int i = 0; i < 4; ++i) {
      const int lrow = i * 4 + srow4;
      const int psw2 = (lrow & 7) << 3;
      f16x2 pv2 = *(const f16x2*)&Ps[(w * 16 + lrow) * 64 + ((cc * 32 + scol) ^ psw2)];
      f32x2 st = {(float)pv2[0], (float)pv2[1]};
      __builtin_nontemporal_store(st,
          (f32x2*)&sRow[(size_t)(wbase + lrow) * NS + (NT - 1) * 64 + cc * 32 + scol]);
    }

  // epilogue: acco col=l15=d, row=lg*4+r=q-offset
#pragma unroll
  for (int c = 0; c < 4; ++c)
#pragma unroll
    for (int r = 0; r < 4; ++r)
      attnW[(size_t)(b * NS + wbase + lg * 4 + r) * ND + h * 64 + c * 16 + l15] =
          (f16)acco[c][r];
}

extern "C" void kernel_launch(void* const* d_in, const int* in_sizes, int n_in,
                              void* d_out, int out_size, void* d_ws, size_t ws_size,
                              hipStream_t stream) {
  const float* q  = (const float*)d_in[0];
  const float* k  = (const float*)d_in[1];
  const float* v  = (const float*)d_in[2];
  const float* Wq = (const float*)d_in[3];
  const float* bq = (const float*)d_in[4];
  const float* Wk = (const float*)d_in[5];
  const float* bk = (const float*)d_in[6];
  const float* Wv = (const float*)d_in[7];
  const float* bv = (const float*)d_in[8];
  const float* Wo = (const float*)d_in[9];
  const float* bo = (const float*)d_in[10];

  float* out  = (float*)d_out;
  float* sOut = out + (size_t)NB * NS * ND;   // s region, 134.2M floats

  const size_t EL = (size_t)NB * NS * ND;     // 4,194,304
  const size_t WL = (size_t)ND * ND;          // 1,048,576

  // fp16 input copies in the (not-yet-written) s region of d_out
  f16* sc  = (f16*)sOut;
  f16 *qf  = sc,            *kf  = sc + EL,      *vf  = sc + 2 * EL;
  f16 *Wq6 = sc + 3 * EL,   *Wk6 = Wq6 + WL,     *Wv6 = Wk6 + WL;

  // d_ws: qh, kh, vhT, attn (8 MB each) + Wo16 (2 MB)
  f16* wsh = (f16*)d_ws;
  f16 *qhW  = wsh,          *khW  = wsh + EL;
  f16 *vhT  = wsh + 3 * EL, *attn = wsh + 4 * EL;
  f16 *Wo6  = wsh + 5 * EL;

  CvtArgs ca;
  ca.src[0]=q;  ca.dst[0]=qf;  ca.n8[0]=(int)(EL/8);
  ca.src[1]=k;  ca.dst[1]=kf;  ca.n8[1]=(int)(EL/8);
  ca.src[2]=v;  ca.dst[2]=vf;  ca.n8[2]=(int)(EL/8);
  ca.src[3]=Wq; ca.dst[3]=Wq6; ca.n8[3]=(int)(WL/8);
  ca.src[4]=Wk; ca.dst[4]=Wk6; ca.n8[4]=(int)(WL/8);
  ca.src[5]=Wv; ca.dst[5]=Wv6; ca.n8[5]=(int)(WL/8);
  ca.src[6]=Wo; ca.dst[6]=Wo6; ca.n8[6]=(int)(WL/8);
  cvt_multi<<<dim3(2048, 7), 256, 0, stream>>>(ca);

  // fused QKV projections; V writes TRANSPOSED [B,H,64,S] directly
  GemmBatch gq;
  gq.op[0] = { qf, Wq6, bq, qhW,    nullptr, nullptr };
  gq.op[1] = { kf, Wk6, bk, khW,    nullptr, nullptr };
  gq.op[2] = { vf, Wv6, bv, nullptr, nullptr, vhT    };
  gemm_nt_f16<<<dim3(32, 8, 3), 256, 0, stream>>>(gq, NB * NS, ND, ND);

  // attention (writes s region + attn), two passes in-kernel
  attn_kernel<<<dim3(1024), 256, 0, stream>>>(qhW, khW, vhT, attn, sOut);

  // output projection
  GemmBatch go;
  go.op[0] = { attn, Wo6, bo, nullptr, out, nullptr };
  go.op[1] = go.op[0];
  go.op[2] = go.op[0];
  gemm_nt_f16<<<dim3(32, 8, 1), 256, 0, stream>>>(go, NB * NS, ND, ND);
}

// Round 19
// 228.841 us; speedup vs baseline: 1.0949x; 1.0401x over previous
//
#include <hip/hip_runtime.h>
#include <math.h>

typedef _Float16 f16;
typedef _Float16 f16x2 __attribute__((ext_vector_type(2)));
typedef _Float16 f16x4 __attribute__((ext_vector_type(4)));
typedef _Float16 f16x8 __attribute__((ext_vector_type(8)));
typedef float f32x2 __attribute__((ext_vector_type(2)));
typedef float f32x4 __attribute__((ext_vector_type(4)));

#define NB   2
#define NS   2048
#define ND   1024
#define NH   16
#define NHD  64
#define EPSF 1e-6f
#define SCL  0.18033688011110793f   // 0.125 * log2(e)
#define EXP2F(x) __builtin_exp2f(x) // lowers to v_exp_f32 (HW is 2^x)

__device__ __forceinline__ void gll16(const void* g, void* l) {
  __builtin_amdgcn_global_load_lds(
      (const __attribute__((address_space(1))) void*)g,
      (__attribute__((address_space(3))) void*)l, 16, 0, 0);
}

// ---------------- fused fp32 -> fp16 convert: 7 tensors, one launch ----------------
struct CvtArgs { const float* src[7]; f16* dst[7]; int n8[7]; };

__global__ void cvt_multi(CvtArgs a) {
  const int ti = blockIdx.y;
  const int i = blockIdx.x * blockDim.x + threadIdx.x;
  if (i >= a.n8[ti]) return;
  const float4* s4 = (const float4*)a.src[ti] + (size_t)i * 2;
  float4 x = s4[0], y = s4[1];
  f16x8 o;
  o[0]=(f16)x.x; o[1]=(f16)x.y; o[2]=(f16)x.z; o[3]=(f16)x.w;
  o[4]=(f16)y.x; o[5]=(f16)y.y; o[6]=(f16)y.z; o[7]=(f16)y.w;
  ((f16x8*)a.dst[ti])[i] = o;
}

// ---------------- GEMM: C[M][N] = A[M][K] * B[N][K]^T + bias ----------------
// 128x128 tile, BK=64, 4 waves, top-sync dbuf. Output paths: f16 row-major (oh),
// f32 row-major (of), or f16 TRANSPOSED per-head [B,H,64,S] (vt - V projection).
struct GemmOps { const f16* A; const f16* Bw; const float* bias; f16* oh; float* of; f16* vt; };
struct GemmBatch { GemmOps op[3]; };

__launch_bounds__(256, 2)
__global__ void gemm_nt_f16(GemmBatch gb, int M, int N, int K) {
  __shared__ f16 As[2][128 * 64];
  __shared__ f16 Bs[2][128 * 64];
  const GemmOps g = gb.op[blockIdx.z];
  const int t = threadIdx.x;
  const int w = t >> 6, l = t & 63, l15 = l & 15, lg = l >> 4;
  const int wr = w >> 1, wc = w & 1;
  const int m0 = blockIdx.x * 128, n0 = blockIdx.y * 128;
  const f16* A = g.A;
  const f16* Bm = g.Bw;

  auto stage = [&](int k0, int b) {
    for (int i = 0; i < 4; ++i) {
      int idx = i * 256 + t;
      int row = idx >> 3, seg = idx & 7;
      gll16(&A[(size_t)(m0 + row) * K + k0 + seg * 8], &As[b][idx * 8]);
      gll16(&Bm[(size_t)(n0 + row) * K + k0 + seg * 8], &Bs[b][idx * 8]);
    }
  };

  f32x4 acc[4][4] = {};
  stage(0, 0);
  int cur = 0;
  const int NT = K / 64;
  for (int kt = 0; kt < NT; ++kt, cur ^= 1) {
    __syncthreads();                       // drains staging kt; fences compiler
    if (kt + 1 < NT) stage((kt + 1) * 64, cur ^ 1);
    for (int kk = 0; kk < 64; kk += 32) {
      f16x8 af[4], bf[4];
      for (int a = 0; a < 4; ++a)
        af[a] = *(const f16x8*)&As[cur][(wr * 64 + a * 16 + l15) * 64 + kk + lg * 8];
      for (int b = 0; b < 4; ++b)
        bf[b] = *(const f16x8*)&Bs[cur][(wc * 64 + b * 16 + l15) * 64 + kk + lg * 8];
      for (int a = 0; a < 4; ++a)
        for (int b = 0; b < 4; ++b)
          acc[a][b] = __builtin_amdgcn_mfma_f32_16x16x32_f16(af[a], bf[b], acc[a][b], 0, 0, 0);
    }
  }
  for (int b = 0; b < 4; ++b) {
    int gcol = n0 + wc * 64 + b * 16 + l15;
    float bv = g.bias[gcol];
    if (g.vt) {
      // transposed V store: vhT[((b_*16+h)*64+d)*NS + s], 4 consecutive s per lane
      const int hh = gcol >> 6, dd = gcol & 63;
      for (int a = 0; a < 4; ++a) {
        int gr = m0 + wr * 64 + a * 16 + lg * 4;
        const int b_ = gr >> 11, s = gr & 2047;
        f16x4 pk;
        for (int r = 0; r < 4; ++r) pk[r] = (f16)(acc[a][b][r] + bv);
        *(f16x4*)&g.vt[((size_t)(b_ * 16 + hh) * 64 + dd) * NS + s] = pk;
      }
    } else {
      for (int a = 0; a < 4; ++a) {
        int gr = m0 + wr * 64 + a * 16 + lg * 4;
        for (int r = 0; r < 4; ++r) {
          float vv = acc[a][b][r] + bv;
          if (g.oh) g.oh[(size_t)(gr + r) * N + gcol] = (f16)vv;
          else      g.of[(size_t)(gr + r) * N + gcol] = vv;
        }
      }
    }
  }
}

// ---------------- attention: R17 + pass-1 4-deep K-ring (2 tiles/sync) ----------
// 1024 blocks (32 bh x 32 q-blocks of 64 rows), 4 waves x 16 q-rows, 4 blocks/CU.
// One shared KR[4] array (no LDS pointer arrays - gfx950 static-init limitation):
// pass 1 uses it as a 4-buffer K ring (16 barriers not 32, each drain 1 iter
// old); pass 2 uses KR[0..1] as the K dbuf and KR[2..3] as the V dbuf.
// pass 2 logic unchanged from R17 (one-tile-deferred full-line s-stores).
__launch_bounds__(256, 4)
__global__ void attn_kernel(const f16* __restrict__ qh, const f16* __restrict__ kh,
                            const f16* __restrict__ vhT, f16* __restrict__ attnW,
                            float* __restrict__ sOut) {
  __shared__ f16 KR[4][64 * 64];   // 32 KB: pass1 K-ring; pass2 K=KR[0..1], V=KR[2..3]
  __shared__ f16 Ps[64 * 64];      // 8 KB, wave-private 16-row stripes, swizzled
  const int t = threadIdx.x, w = t >> 6, l = t & 63, l15 = l & 15, lg = l >> 4;
  const int bid = blockIdx.x;
  const int wg = (bid & 7) * 128 + (bid >> 3);     // bijective XCD swizzle (1024)
  const int bh = wg >> 5, qi = wg & 31;
  const int q0 = qi * 64;
  const int b = bh >> 4, h = bh & 15;
  const f16* Qb = qh + (size_t)(b * NS) * ND + h * 64;
  const f16* Kb = kh + (size_t)(b * NS) * ND + h * 64;
  const f16* Vb = vhT + (size_t)bh * 64 * NS;
  const int NT = NS / 64;

  const int wbase = q0 + w * 16;
  const int dkt  = wbase >> 6;
  const int dbb  = (wbase & 63) >> 4;
  const int dlg = l15 >> 2, dr = l15 & 3;
  const int sw = l15 & 7;

  // K stage into ring buffer ri
  auto stageK = [&](int kt, int ri) {
    for (int i = 0; i < 2; ++i) {
      int idx = i * 256 + t, row = idx >> 3, seg = idx & 7;
      gll16(&Kb[(size_t)(kt * 64 + row) * ND + (seg ^ (row & 7)) * 8], &KR[ri][idx * 8]);
    }
  };
  auto stageV = [&](int kt, int bf) {
    for (int i = 0; i < 2; ++i) {
      int idx = i * 256 + t, row = idx >> 3, seg = idx & 7;
      gll16(&Vb[(size_t)row * NS + kt * 64 + (seg ^ (row & 7)) * 8], &KR[2 + bf][idx * 8]);
    }
  };

  // Q fragments (B-operand): lane l15 = q-col
  f16x8 qf[2];
  qf[0] = *(const f16x8*)&Qb[(size_t)(wbase + l15) * ND + lg * 8];
  qf[1] = *(const f16x8*)&Qb[(size_t)(wbase + l15) * ND + 32 + lg * 8];

  float Zp = 0.f, Dp = 0.f;

  // ---- pass 1: Z and diag sums; 4-buffer K ring, 2 tiles per sync ----
  stageK(0, 0);
  stageK(1, 1);
  for (int kt = 0; kt < NT; kt += 2) {
    __syncthreads();                       // drains stages kt, kt+1 (1 iter old)
    if (kt + 2 < NT) stageK(kt + 2, (kt + 2) & 3);
    if (kt + 3 < NT) stageK(kt + 3, (kt + 3) & 3);
#pragma unroll
    for (int sub = 0; sub < 2; ++sub) {
      const int kc = kt + sub;
      const f16* Kc = KR[kc & 3];
      f32x4 accs[4] = {};
#pragma unroll
      for (int kkI = 0; kkI < 2; ++kkI)
#pragma unroll
        for (int bb = 0; bb < 4; ++bb) {
          f16x8 kf_ = *(const f16x8*)&Kc[(bb * 16 + l15) * 64 + ((kkI * 4 + lg) ^ sw) * 8];
          accs[bb] = __builtin_amdgcn_mfma_f32_16x16x32_f16(kf_, qf[kkI], accs[bb], 0, 0, 0);
        }
#pragma unroll
      for (int bb = 0; bb < 4; ++bb) {
        float e0 = EXP2F(accs[bb][0] * SCL);
        float e1 = EXP2F(accs[bb][1] * SCL);
        float e2 = EXP2F(accs[bb][2] * SCL);
        float e3 = EXP2F(accs[bb][3] * SCL);
        Zp += (e0 + e1) + (e2 + e3);
        if (kc == dkt && bb == dbb && lg == dlg)
          Dp += dr == 0 ? e0 : dr == 1 ? e1 : dr == 2 ? e2 : e3;
      }
    }
  }

  // reduce across the 4 lg groups (same l15 = same q-row)
  float z = Zp, d = Dp;
  z += __shfl_xor(z, 16, 64); z += __shfl_xor(z, 32, 64);
  d += __shfl_xor(d, 16, 64); d += __shfl_xor(d, 32, 64);
  const float rden = 1.f / (z - d + EPSF * z);
  __syncthreads();   // pass-1 ring reads done before pass-2 staging overwrites

  // ---- pass 2: scores -> Ps (swizzled) -> PV; s-store deferred one tile ----
  f32x4 acco[4] = {};
  float* sRow = sOut + (size_t)bh * NS * NS;
  const int prow  = w * 16 + l15;       // this lane's Ps row (write/PV side)
  const int pswz  = (l15 & 7) << 3;     // col-swizzle for that row
  const int srow4 = l >> 4;             // 0..3: row-group for the coalesced store
  const int scol  = (l & 15) * 2;       // f16-pair index within a 32-col chunk
  stageK(0, 0);
  stageV(0, 0);
  int cur = 0;
  for (int kt = 0; kt < NT; ++kt, cur ^= 1) {
    __syncthreads();
    if (kt + 1 < NT) { stageK(kt + 1, cur ^ 1); stageV(kt + 1, cur ^ 1); }
    // deferred flush of tile kt-1's s (Ps still holds it; overwritten below)
    if (kt) {
#pragma unroll
      for (int cc = 0; cc < 2; ++cc)
#pragma unroll
        for (int i = 0; i < 4; ++i) {
          const int lrow = i * 4 + srow4;             // 0..15 within stripe
          const int psw2 = (lrow & 7) << 3;
          f16x2 pv2 = *(const f16x2*)&Ps[(w * 16 + lrow) * 64 + ((cc * 32 + scol) ^ psw2)];
          f32x2 st = {(float)pv2[0], (float)pv2[1]};
          __builtin_nontemporal_store(st,
              (f32x2*)&sRow[(size_t)(wbase + lrow) * NS + (kt - 1) * 64 + cc * 32 + scol]);
        }
    }
    f32x4 accs[4] = {};
#pragma unroll
    for (int kkI = 0; kkI < 2; ++kkI)
#pragma unroll
      for (int bb = 0; bb < 4; ++bb) {
        f16x8 kf_ = *(const f16x8*)&KR[cur][(bb * 16 + l15) * 64 + ((kkI * 4 + lg) ^ sw) * 8];
        accs[bb] = __builtin_amdgcn_mfma_f32_16x16x32_f16(kf_, qf[kkI], accs[bb], 0, 0, 0);
      }
    // two k-chunks of 32; Ps 64-col (swizzled), same-wave LDS ops are in-order
#pragma unroll
    for (int ph = 0; ph < 2; ++ph) {
#pragma unroll
      for (int bbi = 0; bbi < 2; ++bbi) {
        const int bb = ph * 2 + bbi;
        float p0 = EXP2F(accs[bb][0] * SCL) * rden;
        float p1 = EXP2F(accs[bb][1] * SCL) * rden;
        float p2 = EXP2F(accs[bb][2] * SCL) * rden;
        float p3 = EXP2F(accs[bb][3] * SCL) * rden;
        if (kt == dkt && bb == dbb && lg == dlg) {
          if (dr == 0) p0 = 0.f;
          if (dr == 1) p1 = 0.f;
          if (dr == 2) p2 = 0.f;
          if (dr == 3) p3 = 0.f;
        }
        f16x4 phk = {(f16)p0, (f16)p1, (f16)p2, (f16)p3};
        *(f16x4*)&Ps[prow * 64 + ((ph * 32 + bbi * 16 + lg * 4) ^ pswz)] = phk;
      }
      f16x8 pa = *(const f16x8*)&Ps[prow * 64 + ((ph * 32 + lg * 8) ^ pswz)];
#pragma unroll
      for (int c = 0; c < 4; ++c) {
        f16x8 vf_ = *(const f16x8*)&KR[2 + cur][(c * 16 + l15) * 64 + ((ph * 4 + lg) ^ sw) * 8];
        acco[c] = __builtin_amdgcn_mfma_f32_16x16x32_f16(pa, vf_, acco[c], 0, 0, 0);
      }
    }
  }
  // final flush for tile NT-1 (Ps still valid after loop exit)
#pragma unroll
  for (int cc = 0; cc < 2; ++cc)
#pragma unroll
    for (int i = 0; i < 4; ++i) {
      const int lrow = i * 4 + srow4;
      const int psw2 = (lrow & 7) << 3;
      f16x2 pv2 = *(const f16x2*)&Ps[(w * 16 + lrow) * 64 + ((cc * 32 + scol) ^ psw2)];
      f32x2 st = {(float)pv2[0], (float)pv2[1]};
      __builtin_nontemporal_store(st,
          (f32x2*)&sRow[(size_t)(wbase + lrow) * NS + (NT - 1) * 64 + cc * 32 + scol]);
    }

  // epilogue: acco col=l15=d, row=lg*4+r=q-offset
#pragma unroll
  for (int c = 0; c < 4; ++c)
#pragma unroll
    for (int r = 0; r < 4; ++r)
      attnW[(size_t)(b * NS + wbase + lg * 4 + r) * ND + h * 64 + c * 16 + l15] =
          (f16)acco[c][r];
}

extern "C" void kernel_launch(void* const* d_in, const int* in_sizes, int n_in,
                              void* d_out, int out_size, void* d_ws, size_t ws_size,
                              hipStream_t stream) {
  const float* q  = (const float*)d_in[0];
  const float* k  = (const float*)d_in[1];
  const float* v  = (const float*)d_in[2];
  const float* Wq = (const float*)d_in[3];
  const float* bq = (const float*)d_in[4];
  const float* Wk = (const float*)d_in[5];
  const float* bk = (const float*)d_in[6];
  const float* Wv = (const float*)d_in[7];
  const float* bv = (const float*)d_in[8];
  const float* Wo = (const float*)d_in[9];
  const float* bo = (const float*)d_in[10];

  float* out  = (float*)d_out;
  float* sOut = out + (size_t)NB * NS * ND;   // s region, 134.2M floats

  const size_t EL = (size_t)NB * NS * ND;     // 4,194,304
  const size_t WL = (size_t)ND * ND;          // 1,048,576

  // fp16 input copies in the (not-yet-written) s region of d_out
  f16* sc  = (f16*)sOut;
  f16 *qf  = sc,            *kf  = sc + EL,      *vf  = sc + 2 * EL;
  f16 *Wq6 = sc + 3 * EL,   *Wk6 = Wq6 + WL,     *Wv6 = Wk6 + WL;

  // d_ws: qh, kh, vhT, attn (8 MB each) + Wo16 (2 MB)
  f16* wsh = (f16*)d_ws;
  f16 *qhW  = wsh,          *khW  = wsh + EL;
  f16 *vhT  = wsh + 3 * EL, *attn = wsh + 4 * EL;
  f16 *Wo6  = wsh + 5 * EL;

  CvtArgs ca;
  ca.src[0]=q;  ca.dst[0]=qf;  ca.n8[0]=(int)(EL/8);
  ca.src[1]=k;  ca.dst[1]=kf;  ca.n8[1]=(int)(EL/8);
  ca.src[2]=v;  ca.dst[2]=vf;  ca.n8[2]=(int)(EL/8);
  ca.src[3]=Wq; ca.dst[3]=Wq6; ca.n8[3]=(int)(WL/8);
  ca.src[4]=Wk; ca.dst[4]=Wk6; ca.n8[4]=(int)(WL/8);
  ca.src[5]=Wv; ca.dst[5]=Wv6; ca.n8[5]=(int)(WL/8);
  ca.src[6]=Wo; ca.dst[6]=Wo6; ca.n8[6]=(int)(WL/8);
  cvt_multi<<<dim3(2048, 7), 256, 0, stream>>>(ca);

  // fused QKV projections; V writes TRANSPOSED [B,H,64,S] directly
  GemmBatch gq;
  gq.op[0] = { qf, Wq6, bq, qhW,    nullptr, nullptr };
  gq.op[1] = { kf, Wk6, bk, khW,    nullptr, nullptr };
  gq.op[2] = { vf, Wv6, bv, nullptr, nullptr, vhT    };
  gemm_nt_f16<<<dim3(32, 8, 3), 256, 0, stream>>>(gq, NB * NS, ND, ND);

  // attention (writes s region + attn), two passes in-kernel
  attn_kernel<<<dim3(1024), 256, 0, stream>>>(qhW, khW, vhT, attn, sOut);

  // output projection
  GemmBatch go;
  go.op[0] = { attn, Wo6, bo, nullptr, out, nullptr };
  go.op[1] = go.op[0];
  go.op[2] = go.op[0];
  gemm_nt_f16<<<dim3(32, 8, 1), 256, 0, stream>>>(go, NB * NS, ND, ND);
}

// Round 20
// 221.460 us; speedup vs baseline: 1.1314x; 1.0333x over previous
//
#include <hip/hip_runtime.h>
#include <math.h>

typedef _Float16 f16;
typedef _Float16 f16x2 __attribute__((ext_vector_type(2)));
typedef _Float16 f16x4 __attribute__((ext_vector_type(4)));
typedef _Float16 f16x8 __attribute__((ext_vector_type(8)));
typedef float f32x2 __attribute__((ext_vector_type(2)));
typedef float f32x4 __attribute__((ext_vector_type(4)));

#define NB   2
#define NS   2048
#define ND   1024
#define NH   16
#define NHD  64
#define EPSF 1e-6f
#define SCL  0.18033688011110793f   // 0.125 * log2(e)
#define EXP2F(x) __builtin_exp2f(x) // lowers to v_exp_f32 (HW is 2^x)

__device__ __forceinline__ void gll16(const void* g, void* l) {
  __builtin_amdgcn_global_load_lds(
      (const __attribute__((address_space(1))) void*)g,
      (__attribute__((address_space(3))) void*)l, 16, 0, 0);
}

// ---------------- fused fp32 -> fp16 convert: 7 tensors, one launch ----------------
struct CvtArgs { const float* src[7]; f16* dst[7]; int n8[7]; };

__global__ void cvt_multi(CvtArgs a) {
  const int ti = blockIdx.y;
  const int i = blockIdx.x * blockDim.x + threadIdx.x;
  if (i >= a.n8[ti]) return;
  const float4* s4 = (const float4*)a.src[ti] + (size_t)i * 2;
  float4 x = s4[0], y = s4[1];
  f16x8 o;
  o[0]=(f16)x.x; o[1]=(f16)x.y; o[2]=(f16)x.z; o[3]=(f16)x.w;
  o[4]=(f16)y.x; o[5]=(f16)y.y; o[6]=(f16)y.z; o[7]=(f16)y.w;
  ((f16x8*)a.dst[ti])[i] = o;
}

// ---------------- GEMM: C[M][N] = A[M][K] * B[N][K]^T + bias ----------------
// 128x128 tile, BK=32, 4 waves, top-sync dbuf. LDS = 32 KB -> 4+ blocks/CU:
// the 768-block QKV launch is fully resident in ONE dispatch wave (at BK=64 /
// 64 KB it was 2 blocks/CU -> 512 + 256-block tail at half density).
struct GemmOps { const f16* A; const f16* Bw; const float* bias; f16* oh; float* of; f16* vt; };
struct GemmBatch { GemmOps op[3]; };

__launch_bounds__(256, 4)
__global__ void gemm_nt_f16(GemmBatch gb, int M, int N, int K) {
  __shared__ f16 As[2][128 * 32];   // 8 KB each
  __shared__ f16 Bs[2][128 * 32];
  const GemmOps g = gb.op[blockIdx.z];
  const int t = threadIdx.x;
  const int w = t >> 6, l = t & 63, l15 = l & 15, lg = l >> 4;
  const int wr = w >> 1, wc = w & 1;
  const int m0 = blockIdx.x * 128, n0 = blockIdx.y * 128;
  const f16* A = g.A;
  const f16* Bm = g.Bw;

  auto stage = [&](int k0, int b) {
    for (int i = 0; i < 2; ++i) {
      int idx = i * 256 + t;
      int row = idx >> 2, seg = idx & 3;
      gll16(&A[(size_t)(m0 + row) * K + k0 + seg * 8], &As[b][idx * 8]);
      gll16(&Bm[(size_t)(n0 + row) * K + k0 + seg * 8], &Bs[b][idx * 8]);
    }
  };

  f32x4 acc[4][4] = {};
  stage(0, 0);
  int cur = 0;
  const int NT = K / 32;
  for (int kt = 0; kt < NT; ++kt, cur ^= 1) {
    __syncthreads();                       // drains staging kt; fences compiler
    if (kt + 1 < NT) stage((kt + 1) * 32, cur ^ 1);
    f16x8 af[4], bf[4];
    for (int a = 0; a < 4; ++a)
      af[a] = *(const f16x8*)&As[cur][(wr * 64 + a * 16 + l15) * 32 + lg * 8];
    for (int b = 0; b < 4; ++b)
      bf[b] = *(const f16x8*)&Bs[cur][(wc * 64 + b * 16 + l15) * 32 + lg * 8];
    for (int a = 0; a < 4; ++a)
      for (int b = 0; b < 4; ++b)
        acc[a][b] = __builtin_amdgcn_mfma_f32_16x16x32_f16(af[a], bf[b], acc[a][b], 0, 0, 0);
  }
  for (int b = 0; b < 4; ++b) {
    int gcol = n0 + wc * 64 + b * 16 + l15;
    float bv = g.bias[gcol];
    if (g.vt) {
      // transposed V store: vhT[((b_*16+h)*64+d)*NS + s], 4 consecutive s per lane
      const int hh = gcol >> 6, dd = gcol & 63;
      for (int a = 0; a < 4; ++a) {
        int gr = m0 + wr * 64 + a * 16 + lg * 4;
        const int b_ = gr >> 11, s = gr & 2047;
        f16x4 pk;
        for (int r = 0; r < 4; ++r) pk[r] = (f16)(acc[a][b][r] + bv);
        *(f16x4*)&g.vt[((size_t)(b_ * 16 + hh) * 64 + dd) * NS + s] = pk;
      }
    } else {
      for (int a = 0; a < 4; ++a) {
        int gr = m0 + wr * 64 + a * 16 + lg * 4;
        for (int r = 0; r < 4; ++r) {
          float vv = acc[a][b][r] + bv;
          if (g.oh) g.oh[(size_t)(gr + r) * N + gcol] = (f16)vv;
          else      g.of[(size_t)(gr + r) * N + gcol] = vv;
        }
      }
    }
  }
}

// ---------------- attention: R19 (pass-1 4-deep K-ring + deferred s-stores) -----
// 1024 blocks (32 bh x 32 q-blocks of 64 rows), 4 waves x 16 q-rows, 4 blocks/CU.
__launch_bounds__(256, 4)
__global__ void attn_kernel(const f16* __restrict__ qh, const f16* __restrict__ kh,
                            const f16* __restrict__ vhT, f16* __restrict__ attnW,
                            float* __restrict__ sOut) {
  __shared__ f16 KR[4][64 * 64];   // 32 KB: pass1 K-ring; pass2 K=KR[0..1], V=KR[2..3]
  __shared__ f16 Ps[64 * 64];      // 8 KB, wave-private 16-row stripes, swizzled
  const int t = threadIdx.x, w = t >> 6, l = t & 63, l15 = l & 15, lg = l >> 4;
  const int bid = blockIdx.x;
  const int wg = (bid & 7) * 128 + (bid >> 3);     // bijective XCD swizzle (1024)
  const int bh = wg >> 5, qi = wg & 31;
  const int q0 = qi * 64;
  const int b = bh >> 4, h = bh & 15;
  const f16* Qb = qh + (size_t)(b * NS) * ND + h * 64;
  const f16* Kb = kh + (size_t)(b * NS) * ND + h * 64;
  const f16* Vb = vhT + (size_t)bh * 64 * NS;
  const int NT = NS / 64;

  const int wbase = q0 + w * 16;
  const int dkt  = wbase >> 6;
  const int dbb  = (wbase & 63) >> 4;
  const int dlg = l15 >> 2, dr = l15 & 3;
  const int sw = l15 & 7;

  auto stageK = [&](int kt, int ri) {
    for (int i = 0; i < 2; ++i) {
      int idx = i * 256 + t, row = idx >> 3, seg = idx & 7;
      gll16(&Kb[(size_t)(kt * 64 + row) * ND + (seg ^ (row & 7)) * 8], &KR[ri][idx * 8]);
    }
  };
  auto stageV = [&](int kt, int bf) {
    for (int i = 0; i < 2; ++i) {
      int idx = i * 256 + t, row = idx >> 3, seg = idx & 7;
      gll16(&Vb[(size_t)row * NS + kt * 64 + (seg ^ (row & 7)) * 8], &KR[2 + bf][idx * 8]);
    }
  };

  // Q fragments (B-operand): lane l15 = q-col
  f16x8 qf[2];
  qf[0] = *(const f16x8*)&Qb[(size_t)(wbase + l15) * ND + lg * 8];
  qf[1] = *(const f16x8*)&Qb[(size_t)(wbase + l15) * ND + 32 + lg * 8];

  float Zp = 0.f, Dp = 0.f;

  // ---- pass 1: Z and diag sums; 4-buffer K ring, 2 tiles per sync ----
  stageK(0, 0);
  stageK(1, 1);
  for (int kt = 0; kt < NT; kt += 2) {
    __syncthreads();                       // drains stages kt, kt+1 (1 iter old)
    if (kt + 2 < NT) stageK(kt + 2, (kt + 2) & 3);
    if (kt + 3 < NT) stageK(kt + 3, (kt + 3) & 3);
#pragma unroll
    for (int sub = 0; sub < 2; ++sub) {
      const int kc = kt + sub;
      const f16* Kc = KR[kc & 3];
      f32x4 accs[4] = {};
#pragma unroll
      for (int kkI = 0; kkI < 2; ++kkI)
#pragma unroll
        for (int bb = 0; bb < 4; ++bb) {
          f16x8 kf_ = *(const f16x8*)&Kc[(bb * 16 + l15) * 64 + ((kkI * 4 + lg) ^ sw) * 8];
          accs[bb] = __builtin_amdgcn_mfma_f32_16x16x32_f16(kf_, qf[kkI], accs[bb], 0, 0, 0);
        }
#pragma unroll
      for (int bb = 0; bb < 4; ++bb) {
        float e0 = EXP2F(accs[bb][0] * SCL);
        float e1 = EXP2F(accs[bb][1] * SCL);
        float e2 = EXP2F(accs[bb][2] * SCL);
        float e3 = EXP2F(accs[bb][3] * SCL);
        Zp += (e0 + e1) + (e2 + e3);
        if (kc == dkt && bb == dbb && lg == dlg)
          Dp += dr == 0 ? e0 : dr == 1 ? e1 : dr == 2 ? e2 : e3;
      }
    }
  }

  // reduce across the 4 lg groups (same l15 = same q-row)
  float z = Zp, d = Dp;
  z += __shfl_xor(z, 16, 64); z += __shfl_xor(z, 32, 64);
  d += __shfl_xor(d, 16, 64); d += __shfl_xor(d, 32, 64);
  const float rden = 1.f / (z - d + EPSF * z);
  __syncthreads();   // pass-1 ring reads done before pass-2 staging overwrites

  // ---- pass 2: scores -> Ps (swizzled) -> PV; s-store deferred one tile ----
  f32x4 acco[4] = {};
  float* sRow = sOut + (size_t)bh * NS * NS;
  const int prow  = w * 16 + l15;       // this lane's Ps row (write/PV side)
  const int pswz  = (l15 & 7) << 3;     // col-swizzle for that row
  const int srow4 = l >> 4;             // 0..3: row-group for the coalesced store
  const int scol  = (l & 15) * 2;       // f16-pair index within a 32-col chunk
  stageK(0, 0);
  stageV(0, 0);
  int cur = 0;
  for (int kt = 0; kt < NT; ++kt, cur ^= 1) {
    __syncthreads();
    if (kt + 1 < NT) { stageK(kt + 1, cur ^ 1); stageV(kt + 1, cur ^ 1); }
    // deferred flush of tile kt-1's s (Ps still holds it; overwritten below)
    if (kt) {
#pragma unroll
      for (int cc = 0; cc < 2; ++cc)
#pragma unroll
        for (int i = 0; i < 4; ++i) {
          const int lrow = i * 4 + srow4;             // 0..15 within stripe
          const int psw2 = (lrow & 7) << 3;
          f16x2 pv2 = *(const f16x2*)&Ps[(w * 16 + lrow) * 64 + ((cc * 32 + scol) ^ psw2)];
          f32x2 st = {(float)pv2[0], (float)pv2[1]};
          __builtin_nontemporal_store(st,
              (f32x2*)&sRow[(size_t)(wbase + lrow) * NS + (kt - 1) * 64 + cc * 32 + scol]);
        }
    }
    f32x4 accs[4] = {};
#pragma unroll
    for (int kkI = 0; kkI < 2; ++kkI)
#pragma unroll
      for (int bb = 0; bb < 4; ++bb) {
        f16x8 kf_ = *(const f16x8*)&KR[cur][(bb * 16 + l15) * 64 + ((kkI * 4 + lg) ^ sw) * 8];
        accs[bb] = __builtin_amdgcn_mfma_f32_16x16x32_f16(kf_, qf[kkI], accs[bb], 0, 0, 0);
      }
    // two k-chunks of 32; Ps 64-col (swizzled), same-wave LDS ops are in-order
#pragma unroll
    for (int ph = 0; ph < 2; ++ph) {
#pragma unroll
      for (int bbi = 0; bbi < 2; ++bbi) {
        const int bb = ph * 2 + bbi;
        float p0 = EXP2F(accs[bb][0] * SCL) * rden;
        float p1 = EXP2F(accs[bb][1] * SCL) * rden;
        float p2 = EXP2F(accs[bb][2] * SCL) * rden;
        float p3 = EXP2F(accs[bb][3] * SCL) * rden;
        if (kt == dkt && bb == dbb && lg == dlg) {
          if (dr == 0) p0 = 0.f;
          if (dr == 1) p1 = 0.f;
          if (dr == 2) p2 = 0.f;
          if (dr == 3) p3 = 0.f;
        }
        f16x4 phk = {(f16)p0, (f16)p1, (f16)p2, (f16)p3};
        *(f16x4*)&Ps[prow * 64 + ((ph * 32 + bbi * 16 + lg * 4) ^ pswz)] = phk;
      }
      f16x8 pa = *(const f16x8*)&Ps[prow * 64 + ((ph * 32 + lg * 8) ^ pswz)];
#pragma unroll
      for (int c = 0; c < 4; ++c) {
        f16x8 vf_ = *(const f16x8*)&KR[2 + cur][(c * 16 + l15) * 64 + ((ph * 4 + lg) ^ sw) * 8];
        acco[c] = __builtin_amdgcn_mfma_f32_16x16x32_f16(pa, vf_, acco[c], 0, 0, 0);
      }
    }
  }
  // final flush for tile NT-1 (Ps still valid after loop exit)
#pragma unroll
  for (int cc = 0; cc < 2; ++cc)
#pragma unroll
    for (int i = 0; i < 4; ++i) {
      const int lrow = i * 4 + srow4;
      const int psw2 = (lrow & 7) << 3;
      f16x2 pv2 = *(const f16x2*)&Ps[(w * 16 + lrow) * 64 + ((cc * 32 + scol) ^ psw2)];
      f32x2 st = {(float)pv2[0], (float)pv2[1]};
      __builtin_nontemporal_store(st,
          (f32x2*)&sRow[(size_t)(wbase + lrow) * NS + (NT - 1) * 64 + cc * 32 + scol]);
    }

  // epilogue: acco col=l15=d, row=lg*4+r=q-offset
#pragma unroll
  for (int c = 0; c < 4; ++c)
#pragma unroll
    for (int r = 0; r < 4; ++r)
      attnW[(size_t)(b * NS + wbase + lg * 4 + r) * ND + h * 64 + c * 16 + l15] =
          (f16)acco[c][r];
}

extern "C" void kernel_launch(void* const* d_in, const int* in_sizes, int n_in,
                              void* d_out, int out_size, void* d_ws, size_t ws_size,
                              hipStream_t stream) {
  const float* q  = (const float*)d_in[0];
  const float* k  = (const float*)d_in[1];
  const float* v  = (const float*)d_in[2];
  const float* Wq = (const float*)d_in[3];
  const float* bq = (const float*)d_in[4];
  const float* Wk = (const float*)d_in[5];
  const float* bk = (const float*)d_in[6];
  const float* Wv = (const float*)d_in[7];
  const float* bv = (const float*)d_in[8];
  const float* Wo = (const float*)d_in[9];
  const float* bo = (const float*)d_in[10];

  float* out  = (float*)d_out;
  float* sOut = out + (size_t)NB * NS * ND;   // s region, 134.2M floats

  const size_t EL = (size_t)NB * NS * ND;     // 4,194,304
  const size_t WL = (size_t)ND * ND;          // 1,048,576

  // fp16 input copies in the (not-yet-written) s region of d_out
  f16* sc  = (f16*)sOut;
  f16 *qf  = sc,            *kf  = sc + EL,      *vf  = sc + 2 * EL;
  f16 *Wq6 = sc + 3 * EL,   *Wk6 = Wq6 + WL,     *Wv6 = Wk6 + WL;

  // d_ws: qh, kh, vhT, attn (8 MB each) + Wo16 (2 MB)
  f16* wsh = (f16*)d_ws;
  f16 *qhW  = wsh,          *khW  = wsh + EL;
  f16 *vhT  = wsh + 3 * EL, *attn = wsh + 4 * EL;
  f16 *Wo6  = wsh + 5 * EL;

  CvtArgs ca;
  ca.src[0]=q;  ca.dst[0]=qf;  ca.n8[0]=(int)(EL/8);
  ca.src[1]=k;  ca.dst[1]=kf;  ca.n8[1]=(int)(EL/8);
  ca.src[2]=v;  ca.dst[2]=vf;  ca.n8[2]=(int)(EL/8);
  ca.src[3]=Wq; ca.dst[3]=Wq6; ca.n8[3]=(int)(WL/8);
  ca.src[4]=Wk; ca.dst[4]=Wk6; ca.n8[4]=(int)(WL/8);
  ca.src[5]=Wv; ca.dst[5]=Wv6; ca.n8[5]=(int)(WL/8);
  ca.src[6]=Wo; ca.dst[6]=Wo6; ca.n8[6]=(int)(WL/8);
  cvt_multi<<<dim3(2048, 7), 256, 0, stream>>>(ca);

  // fused QKV projections; V writes TRANSPOSED [B,H,64,S] directly
  GemmBatch gq;
  gq.op[0] = { qf, Wq6, bq, qhW,    nullptr, nullptr };
  gq.op[1] = { kf, Wk6, bk, khW,    nullptr, nullptr };
  gq.op[2] = { vf, Wv6, bv, nullptr, nullptr, vhT    };
  gemm_nt_f16<<<dim3(32, 8, 3), 256, 0, stream>>>(gq, NB * NS, ND, ND);

  // attention (writes s region + attn), two passes in-kernel
  attn_kernel<<<dim3(1024), 256, 0, stream>>>(qhW, khW, vhT, attn, sOut);

  // output projection
  GemmBatch go;
  go.op[0] = { attn, Wo6, bo, nullptr, out, nullptr };
  go.op[1] = go.op[0];
  go.op[2] = go.op[0];
  gemm_nt_f16<<<dim3(32, 8, 1), 256, 0, stream>>>(go, NB * NS, ND, ND);
}

// Round 21
// 219.859 us; speedup vs baseline: 1.1396x; 1.0073x over previous
//
#include <hip/hip_runtime.h>
#include <math.h>

typedef _Float16 f16;
typedef _Float16 f16x2 __attribute__((ext_vector_type(2)));
typedef _Float16 f16x4 __attribute__((ext_vector_type(4)));
typedef _Float16 f16x8 __attribute__((ext_vector_type(8)));
typedef float f32x2 __attribute__((ext_vector_type(2)));
typedef float f32x4 __attribute__((ext_vector_type(4)));

#define NB   2
#define NS   2048
#define ND   1024
#define NH   16
#define NHD  64
#define EPSF 1e-6f
#define SCL  0.18033688011110793f   // 0.125 * log2(e)
#define EXP2F(x) __builtin_exp2f(x) // lowers to v_exp_f32 (HW is 2^x)

__device__ __forceinline__ void gll16(const void* g, void* l) {
  __builtin_amdgcn_global_load_lds(
      (const __attribute__((address_space(1))) void*)g,
      (__attribute__((address_space(3))) void*)l, 16, 0, 0);
}

// ---------------- fused fp32 -> fp16 convert: 7 tensors, one launch ----------------
struct CvtArgs { const float* src[7]; f16* dst[7]; int n8[7]; };

__global__ void cvt_multi(CvtArgs a) {
  const int ti = blockIdx.y;
  const int i = blockIdx.x * blockDim.x + threadIdx.x;
  if (i >= a.n8[ti]) return;
  const float4* s4 = (const float4*)a.src[ti] + (size_t)i * 2;
  float4 x = s4[0], y = s4[1];
  f16x8 o;
  o[0]=(f16)x.x; o[1]=(f16)x.y; o[2]=(f16)x.z; o[3]=(f16)x.w;
  o[4]=(f16)y.x; o[5]=(f16)y.y; o[6]=(f16)y.z; o[7]=(f16)y.w;
  ((f16x8*)a.dst[ti])[i] = o;
}

// ---------------- GEMM: C[M][N] = A[M][K] * B[N][K]^T + bias ----------------
// 128x128 tile, BK=32, 4 waves, top-sync dbuf. LDS = 32 KB -> 4 blocks/CU.
struct GemmOps { const f16* A; const f16* Bw; const float* bias; f16* oh; float* of; f16* vt; };
struct GemmBatch { GemmOps op[3]; };

__launch_bounds__(256, 4)
__global__ void gemm_nt_f16(GemmBatch gb, int M, int N, int K) {
  __shared__ f16 As[2][128 * 32];   // 8 KB each
  __shared__ f16 Bs[2][128 * 32];
  const GemmOps g = gb.op[blockIdx.z];
  const int t = threadIdx.x;
  const int w = t >> 6, l = t & 63, l15 = l & 15, lg = l >> 4;
  const int wr = w >> 1, wc = w & 1;
  const int m0 = blockIdx.x * 128, n0 = blockIdx.y * 128;
  const f16* A = g.A;
  const f16* Bm = g.Bw;

  auto stage = [&](int k0, int b) {
    for (int i = 0; i < 2; ++i) {
      int idx = i * 256 + t;
      int row = idx >> 2, seg = idx & 3;
      gll16(&A[(size_t)(m0 + row) * K + k0 + seg * 8], &As[b][idx * 8]);
      gll16(&Bm[(size_t)(n0 + row) * K + k0 + seg * 8], &Bs[b][idx * 8]);
    }
  };

  f32x4 acc[4][4] = {};
  stage(0, 0);
  int cur = 0;
  const int NT = K / 32;
  for (int kt = 0; kt < NT; ++kt, cur ^= 1) {
    __syncthreads();                       // drains staging kt; fences compiler
    if (kt + 1 < NT) stage((kt + 1) * 32, cur ^ 1);
    f16x8 af[4], bf[4];
    for (int a = 0; a < 4; ++a)
      af[a] = *(const f16x8*)&As[cur][(wr * 64 + a * 16 + l15) * 32 + lg * 8];
    for (int b = 0; b < 4; ++b)
      bf[b] = *(const f16x8*)&Bs[cur][(wc * 64 + b * 16 + l15) * 32 + lg * 8];
    for (int a = 0; a < 4; ++a)
      for (int b = 0; b < 4; ++b)
        acc[a][b] = __builtin_amdgcn_mfma_f32_16x16x32_f16(af[a], bf[b], acc[a][b], 0, 0, 0);
  }
  for (int b = 0; b < 4; ++b) {
    int gcol = n0 + wc * 64 + b * 16 + l15;
    float bv = g.bias[gcol];
    if (g.vt) {
      // transposed V store: vhT[((b_*16+h)*64+d)*NS + s], 4 consecutive s per lane
      const int hh = gcol >> 6, dd = gcol & 63;
      for (int a = 0; a < 4; ++a) {
        int gr = m0 + wr * 64 + a * 16 + lg * 4;
        const int b_ = gr >> 11, s = gr & 2047;
        f16x4 pk;
        for (int r = 0; r < 4; ++r) pk[r] = (f16)(acc[a][b][r] + bv);
        *(f16x4*)&g.vt[((size_t)(b_ * 16 + hh) * 64 + dd) * NS + s] = pk;
      }
    } else {
      for (int a = 0; a < 4; ++a) {
        int gr = m0 + wr * 64 + a * 16 + lg * 4;
        for (int r = 0; r < 4; ++r) {
          float vv = acc[a][b][r] + bv;
          if (g.oh) g.oh[(size_t)(gr + r) * N + gcol] = (f16)vv;
          else      g.of[(size_t)(gr + r) * N + gcol] = vv;
        }
      }
    }
  }
}

// ---------------- GEMM m64: 64x128 tile, 4 waves x (16 x 128) strips ----------
// For the O-projection: 512 blocks (vs 256) -> 2 blocks/CU, 8 waves/CU, no tail.
// Same MFMA mapping as gemm_nt_f16 with a=0 only; acc[8] N-frags per wave.
__launch_bounds__(256, 4)
__global__ void gemm_nt_f16_m64(const f16* __restrict__ A, const f16* __restrict__ Bm,
                                const float* __restrict__ bias, float* __restrict__ of,
                                int M, int N, int K) {
  __shared__ f16 As[2][64 * 32];    // 4 KB each
  __shared__ f16 Bs[2][128 * 32];   // 8 KB each
  const int t = threadIdx.x;
  const int w = t >> 6, l = t & 63, l15 = l & 15, lg = l >> 4;
  const int m0 = blockIdx.x * 64, n0 = blockIdx.y * 128;

  auto stage = [&](int k0, int b) {
    {
      int idx = t, row = idx >> 2, seg = idx & 3;
      gll16(&A[(size_t)(m0 + row) * K + k0 + seg * 8], &As[b][idx * 8]);
    }
    for (int i = 0; i < 2; ++i) {
      int idx = i * 256 + t, row = idx >> 2, seg = idx & 3;
      gll16(&Bm[(size_t)(n0 + row) * K + k0 + seg * 8], &Bs[b][idx * 8]);
    }
  };

  f32x4 acc[8] = {};
  stage(0, 0);
  int cur = 0;
  const int NT = K / 32;
  for (int kt = 0; kt < NT; ++kt, cur ^= 1) {
    __syncthreads();
    if (kt + 1 < NT) stage((kt + 1) * 32, cur ^ 1);
    f16x8 af = *(const f16x8*)&As[cur][(w * 16 + l15) * 32 + lg * 8];
#pragma unroll
    for (int b = 0; b < 8; ++b) {
      f16x8 bf = *(const f16x8*)&Bs[cur][(b * 16 + l15) * 32 + lg * 8];
      acc[b] = __builtin_amdgcn_mfma_f32_16x16x32_f16(af, bf, acc[b], 0, 0, 0);
    }
  }
#pragma unroll
  for (int b = 0; b < 8; ++b) {
    int gcol = n0 + b * 16 + l15;
    float bv = bias[gcol];
    int gr = m0 + w * 16 + lg * 4;
#pragma unroll
    for (int r = 0; r < 4; ++r)
      of[(size_t)(gr + r) * N + gcol] = acc[b][r] + bv;
  }
}

// ---------------- attention: R19 (pass-1 4-deep K-ring + deferred s-stores) -----
// 1024 blocks (32 bh x 32 q-blocks of 64 rows), 4 waves x 16 q-rows, 4 blocks/CU.
__launch_bounds__(256, 4)
__global__ void attn_kernel(const f16* __restrict__ qh, const f16* __restrict__ kh,
                            const f16* __restrict__ vhT, f16* __restrict__ attnW,
                            float* __restrict__ sOut) {
  __shared__ f16 KR[4][64 * 64];   // 32 KB: pass1 K-ring; pass2 K=KR[0..1], V=KR[2..3]
  __shared__ f16 Ps[64 * 64];      // 8 KB, wave-private 16-row stripes, swizzled
  const int t = threadIdx.x, w = t >> 6, l = t & 63, l15 = l & 15, lg = l >> 4;
  const int bid = blockIdx.x;
  const int wg = (bid & 7) * 128 + (bid >> 3);     // bijective XCD swizzle (1024)
  const int bh = wg >> 5, qi = wg & 31;
  const int q0 = qi * 64;
  const int b = bh >> 4, h = bh & 15;
  const f16* Qb = qh + (size_t)(b * NS) * ND + h * 64;
  const f16* Kb = kh + (size_t)(b * NS) * ND + h * 64;
  const f16* Vb = vhT + (size_t)bh * 64 * NS;
  const int NT = NS / 64;

  const int wbase = q0 + w * 16;
  const int dkt  = wbase >> 6;
  const int dbb  = (wbase & 63) >> 4;
  const int dlg = l15 >> 2, dr = l15 & 3;
  const int sw = l15 & 7;

  auto stageK = [&](int kt, int ri) {
    for (int i = 0; i < 2; ++i) {
      int idx = i * 256 + t, row = idx >> 3, seg = idx & 7;
      gll16(&Kb[(size_t)(kt * 64 + row) * ND + (seg ^ (row & 7)) * 8], &KR[ri][idx * 8]);
    }
  };
  auto stageV = [&](int kt, int bf) {
    for (int i = 0; i < 2; ++i) {
      int idx = i * 256 + t, row = idx >> 3, seg = idx & 7;
      gll16(&Vb[(size_t)row * NS + kt * 64 + (seg ^ (row & 7)) * 8], &KR[2 + bf][idx * 8]);
    }
  };

  // Q fragments (B-operand): lane l15 = q-col
  f16x8 qf[2];
  qf[0] = *(const f16x8*)&Qb[(size_t)(wbase + l15) * ND + lg * 8];
  qf[1] = *(const f16x8*)&Qb[(size_t)(wbase + l15) * ND + 32 + lg * 8];

  float Zp = 0.f, Dp = 0.f;

  // ---- pass 1: Z and diag sums; 4-buffer K ring, 2 tiles per sync ----
  stageK(0, 0);
  stageK(1, 1);
  for (int kt = 0; kt < NT; kt += 2) {
    __syncthreads();                       // drains stages kt, kt+1 (1 iter old)
    if (kt + 2 < NT) stageK(kt + 2, (kt + 2) & 3);
    if (kt + 3 < NT) stageK(kt + 3, (kt + 3) & 3);
#pragma unroll
    for (int sub = 0; sub < 2; ++sub) {
      const int kc = kt + sub;
      const f16* Kc = KR[kc & 3];
      f32x4 accs[4] = {};
#pragma unroll
      for (int kkI = 0; kkI < 2; ++kkI)
#pragma unroll
        for (int bb = 0; bb < 4; ++bb) {
          f16x8 kf_ = *(const f16x8*)&Kc[(bb * 16 + l15) * 64 + ((kkI * 4 + lg) ^ sw) * 8];
          accs[bb] = __builtin_amdgcn_mfma_f32_16x16x32_f16(kf_, qf[kkI], accs[bb], 0, 0, 0);
        }
#pragma unroll
      for (int bb = 0; bb < 4; ++bb) {
        float e0 = EXP2F(accs[bb][0] * SCL);
        float e1 = EXP2F(accs[bb][1] * SCL);
        float e2 = EXP2F(accs[bb][2] * SCL);
        float e3 = EXP2F(accs[bb][3] * SCL);
        Zp += (e0 + e1) + (e2 + e3);
        if (kc == dkt && bb == dbb && lg == dlg)
          Dp += dr == 0 ? e0 : dr == 1 ? e1 : dr == 2 ? e2 : e3;
      }
    }
  }

  // reduce across the 4 lg groups (same l15 = same q-row)
  float z = Zp, d = Dp;
  z += __shfl_xor(z, 16, 64); z += __shfl_xor(z, 32, 64);
  d += __shfl_xor(d, 16, 64); d += __shfl_xor(d, 32, 64);
  const float rden = 1.f / (z - d + EPSF * z);
  __syncthreads();   // pass-1 ring reads done before pass-2 staging overwrites

  // ---- pass 2: scores -> Ps (swizzled) -> PV; s-store deferred one tile ----
  f32x4 acco[4] = {};
  float* sRow = sOut + (size_t)bh * NS * NS;
  const int prow  = w * 16 + l15;       // this lane's Ps row (write/PV side)
  const int pswz  = (l15 & 7) << 3;     // col-swizzle for that row
  const int srow4 = l >> 4;             // 0..3: row-group for the coalesced store
  const int scol  = (l & 15) * 2;       // f16-pair index within a 32-col chunk
  stageK(0, 0);
  stageV(0, 0);
  int cur = 0;
  for (int kt = 0; kt < NT; ++kt, cur ^= 1) {
    __syncthreads();
    if (kt + 1 < NT) { stageK(kt + 1, cur ^ 1); stageV(kt + 1, cur ^ 1); }
    // deferred flush of tile kt-1's s (Ps still holds it; overwritten below)
    if (kt) {
#pragma unroll
      for (int cc = 0; cc < 2; ++cc)
#pragma unroll
        for (int i = 0; i < 4; ++i) {
          const int lrow = i * 4 + srow4;             // 0..15 within stripe
          const int psw2 = (lrow & 7) << 3;
          f16x2 pv2 = *(const f16x2*)&Ps[(w * 16 + lrow) * 64 + ((cc * 32 + scol) ^ psw2)];
          f32x2 st = {(float)pv2[0], (float)pv2[1]};
          __builtin_nontemporal_store(st,
              (f32x2*)&sRow[(size_t)(wbase + lrow) * NS + (kt - 1) * 64 + cc * 32 + scol]);
        }
    }
    f32x4 accs[4] = {};
#pragma unroll
    for (int kkI = 0; kkI < 2; ++kkI)
#pragma unroll
      for (int bb = 0; bb < 4; ++bb) {
        f16x8 kf_ = *(const f16x8*)&KR[cur][(bb * 16 + l15) * 64 + ((kkI * 4 + lg) ^ sw) * 8];
        accs[bb] = __builtin_amdgcn_mfma_f32_16x16x32_f16(kf_, qf[kkI], accs[bb], 0, 0, 0);
      }
    // two k-chunks of 32; Ps 64-col (swizzled), same-wave LDS ops are in-order
#pragma unroll
    for (int ph = 0; ph < 2; ++ph) {
#pragma unroll
      for (int bbi = 0; bbi < 2; ++bbi) {
        const int bb = ph * 2 + bbi;
        float p0 = EXP2F(accs[bb][0] * SCL) * rden;
        float p1 = EXP2F(accs[bb][1] * SCL) * rden;
        float p2 = EXP2F(accs[bb][2] * SCL) * rden;
        float p3 = EXP2F(accs[bb][3] * SCL) * rden;
        if (kt == dkt && bb == dbb && lg == dlg) {
          if (dr == 0) p0 = 0.f;
          if (dr == 1) p1 = 0.f;
          if (dr == 2) p2 = 0.f;
          if (dr == 3) p3 = 0.f;
        }
        f16x4 phk = {(f16)p0, (f16)p1, (f16)p2, (f16)p3};
        *(f16x4*)&Ps[prow * 64 + ((ph * 32 + bbi * 16 + lg * 4) ^ pswz)] = phk;
      }
      f16x8 pa = *(const f16x8*)&Ps[prow * 64 + ((ph * 32 + lg * 8) ^ pswz)];
#pragma unroll
      for (int c = 0; c < 4; ++c) {
        f16x8 vf_ = *(const f16x8*)&KR[2 + cur][(c * 16 + l15) * 64 + ((ph * 4 + lg) ^ sw) * 8];
        acco[c] = __builtin_amdgcn_mfma_f32_16x16x32_f16(pa, vf_, acco[c], 0, 0, 0);
      }
    }
  }
  // final flush for tile NT-1 (Ps still valid after loop exit)
#pragma unroll
  for (int cc = 0; cc < 2; ++cc)
#pragma unroll
    for (int i = 0; i < 4; ++i) {
      const int lrow = i * 4 + srow4;
      const int psw2 = (lrow & 7) << 3;
      f16x2 pv2 = *(const f16x2*)&Ps[(w * 16 + lrow) * 64 + ((cc * 32 + scol) ^ psw2)];
      f32x2 st = {(float)pv2[0], (float)pv2[1]};
      __builtin_nontemporal_store(st,
          (f32x2*)&sRow[(size_t)(wbase + lrow) * NS + (NT - 1) * 64 + cc * 32 + scol]);
    }

  // epilogue: acco col=l15=d, row=lg*4+r=q-offset
#pragma unroll
  for (int c = 0; c < 4; ++c)
#pragma unroll
    for (int r = 0; r < 4; ++r)
      attnW[(size_t)(b * NS + wbase + lg * 4 + r) * ND + h * 64 + c * 16 + l15] =
          (f16)acco[c][r];
}

extern "C" void kernel_launch(void* const* d_in, const int* in_sizes, int n_in,
                              void* d_out, int out_size, void* d_ws, size_t ws_size,
                              hipStream_t stream) {
  const float* q  = (const float*)d_in[0];
  const float* k  = (const float*)d_in[1];
  const float* v  = (const float*)d_in[2];
  const float* Wq = (const float*)d_in[3];
  const float* bq = (const float*)d_in[4];
  const float* Wk = (const float*)d_in[5];
  const float* bk = (const float*)d_in[6];
  const float* Wv = (const float*)d_in[7];
  const float* bv = (const float*)d_in[8];
  const float* Wo = (const float*)d_in[9];
  const float* bo = (const float*)d_in[10];

  float* out  = (float*)d_out;
  float* sOut = out + (size_t)NB * NS * ND;   // s region, 134.2M floats

  const size_t EL = (size_t)NB * NS * ND;     // 4,194,304
  const size_t WL = (size_t)ND * ND;          // 1,048,576

  // fp16 input copies in the (not-yet-written) s region of d_out
  f16* sc  = (f16*)sOut;
  f16 *qf  = sc,            *kf  = sc + EL,      *vf  = sc + 2 * EL;
  f16 *Wq6 = sc + 3 * EL,   *Wk6 = Wq6 + WL,     *Wv6 = Wk6 + WL;

  // d_ws: qh, kh, vhT, attn (8 MB each) + Wo16 (2 MB)
  f16* wsh = (f16*)d_ws;
  f16 *qhW  = wsh,          *khW  = wsh + EL;
  f16 *vhT  = wsh + 3 * EL, *attn = wsh + 4 * EL;
  f16 *Wo6  = wsh + 5 * EL;

  CvtArgs ca;
  ca.src[0]=q;  ca.dst[0]=qf;  ca.n8[0]=(int)(EL/8);
  ca.src[1]=k;  ca.dst[1]=kf;  ca.n8[1]=(int)(EL/8);
  ca.src[2]=v;  ca.dst[2]=vf;  ca.n8[2]=(int)(EL/8);
  ca.src[3]=Wq; ca.dst[3]=Wq6; ca.n8[3]=(int)(WL/8);
  ca.src[4]=Wk; ca.dst[4]=Wk6; ca.n8[4]=(int)(WL/8);
  ca.src[5]=Wv; ca.dst[5]=Wv6; ca.n8[5]=(int)(WL/8);
  ca.src[6]=Wo; ca.dst[6]=Wo6; ca.n8[6]=(int)(WL/8);
  cvt_multi<<<dim3(2048, 7), 256, 0, stream>>>(ca);

  // fused QKV projections; V writes TRANSPOSED [B,H,64,S] directly
  GemmBatch gq;
  gq.op[0] = { qf, Wq6, bq, qhW,    nullptr, nullptr };
  gq.op[1] = { kf, Wk6, bk, khW,    nullptr, nullptr };
  gq.op[2] = { vf, Wv6, bv, nullptr, nullptr, vhT    };
  gemm_nt_f16<<<dim3(32, 8, 3), 256, 0, stream>>>(gq, NB * NS, ND, ND);

  // attention (writes s region + attn), two passes in-kernel
  attn_kernel<<<dim3(1024), 256, 0, stream>>>(qhW, khW, vhT, attn, sOut);

  // output projection: 64x128 tiles -> 512 blocks, 2 blocks/CU (was 1)
  gemm_nt_f16_m64<<<dim3(64, 8), 256, 0, stream>>>(attn, Wo6, bo, out, NB * NS, ND, ND);
}